// Round 4
// baseline (692.288 us; speedup 1.0000x reference)
//
#include <hip/hip_runtime.h>
#include <hip/hip_bf16.h>
#include <math.h>

#define DIM   384
#define HEADS 8
#define HD    48
#define NTOK  32768   // 8 * 64 * 64
#define NWIN  512     // 8 images * 64 windows

typedef __attribute__((ext_vector_type(8))) short bf16x8;
typedef __attribute__((ext_vector_type(8))) unsigned short u16x8;
typedef __attribute__((ext_vector_type(4))) float f32x4;

__device__ __forceinline__ float bf2f(unsigned short u) {
    unsigned int v = ((unsigned int)u) << 16;
    return __uint_as_float(v);
}
__device__ __forceinline__ unsigned short f2bf(float f) {
    unsigned int x = __float_as_uint(f);
    unsigned int r = (x + 0x7fffu + ((x >> 16) & 1u)) >> 16;  // RNE
    return (unsigned short)r;
}

// branchless erf-based GELU (A&S 7.1.25 3-term, |err_erf| < 2.5e-5 << bf16 ulp)
__device__ __forceinline__ float gelu(float v) {
    float z  = v * 0.70710678118654752f;
    float az = fabsf(z);
    float t  = __builtin_amdgcn_rcpf(1.0f + 0.47047f * az);
    float p  = t * (0.3480242f + t * (-0.0958798f + t * 0.7478556f));
    float ea = 1.0f - p * __expf(-az * az);
    float er = copysignf(ea, z);
    return 0.5f * v * (1.0f + er);
}

// token (window order) -> source pixel of x (accounting for roll by -SHIFT)
__device__ __forceinline__ void tok2src(int tok, int& b, int& hs, int& ws) {
    int bb  = tok >> 12;
    int win = (tok >> 6) & 63;
    int t   = tok & 63;
    int hi = win >> 3, wi = win & 7;
    int r  = t >> 3,  cc = t & 7;
    b  = bb;
    hs = (hi * 8 + r  + 4) & 63;
    ws = (wi * 8 + cc + 4) & 63;
}

// ------------- merged weight convert: 4 segments f32 [K][N] -> bf16 [N][K] --
__global__ __launch_bounds__(256) void k_wt4(const float* __restrict__ qkv_w,
                                             const float* __restrict__ proj_w,
                                             const float* __restrict__ w1,
                                             const float* __restrict__ w2,
                                             unsigned short* __restrict__ d0,
                                             unsigned short* __restrict__ d1,
                                             unsigned short* __restrict__ d2,
                                             unsigned short* __restrict__ d3) {
    int idx = blockIdx.x * 256 + threadIdx.x;
    const float* W; unsigned short* Wt; int K, N, loc;
    if (idx < 442368)       { W = qkv_w;  Wt = d0; K = 384;  N = 1152; loc = idx; }
    else if (idx < 589824)  { W = proj_w; Wt = d1; K = 384;  N = 384;  loc = idx - 442368; }
    else if (idx < 1179648) { W = w1;     Wt = d2; K = 384;  N = 1536; loc = idx - 589824; }
    else                    { W = w2;     Wt = d3; K = 1536; N = 384;  loc = idx - 1179648; }
    int n = loc / K, k = loc - n * K;
    Wt[loc] = f2bf(W[(size_t)k * N + n]);
}

// -------- gather + LayerNorm1, per (b, image-row hs), coalesced ------------
__global__ __launch_bounds__(256) void k_ln1(const float* __restrict__ x,
                                             const float* __restrict__ g,
                                             const float* __restrict__ bt,
                                             unsigned short* __restrict__ ln1) {
    int blk = blockIdx.x;           // b*64 + hs
    int b  = blk >> 6, hs = blk & 63;
    int t  = threadIdx.x;
    int w  = t & 63, cg = t >> 6;   // pixel, channel-group (4)
    const float* row = x + (size_t)b * DIM * 4096 + hs * 64;

    float sum = 0.f, sq = 0.f;
    for (int i = 0; i < 96; i++) {
        int c = i * 4 + cg;
        float v = row[(size_t)c * 4096 + w];
        sum += v; sq += v * v;
    }
    __shared__ float red[2][4][64];
    __shared__ float mean_s[64], rstd_s[64];
    red[0][cg][w] = sum; red[1][cg][w] = sq;
    __syncthreads();
    if (t < 64) {
        float s  = red[0][0][t] + red[0][1][t] + red[0][2][t] + red[0][3][t];
        float q2 = red[1][0][t] + red[1][1][t] + red[1][2][t] + red[1][3][t];
        float mean = s * (1.0f / DIM);
        float var  = q2 * (1.0f / DIM) - mean * mean;
        mean_s[t] = mean;
        rstd_s[t] = rsqrtf(var + 1e-5f);
    }
    __syncthreads();

    int wp = t >> 2, seg = t & 3;
    int hr = (hs + 60) & 63, wr = (wp + 60) & 63;
    int tok = ((b * 8 + (hr >> 3)) * 8 + (wr >> 3)) * 64 + (hr & 7) * 8 + (wr & 7);

    __shared__ __align__(16) unsigned short tile[64][72];
    for (int chunk = 0; chunk < 6; chunk++) {
        float mean = mean_s[w], rstd = rstd_s[w];
        #pragma unroll
        for (int it = 0; it < 16; it++) {
            int cl = it * 4 + cg;
            int c  = chunk * 64 + cl;
            float v = row[(size_t)c * 4096 + w];
            tile[w][cl] = f2bf((v - mean) * rstd * g[c] + bt[c]);
        }
        __syncthreads();
        u16x8 v0 = *(const u16x8*)&tile[wp][seg * 16];
        u16x8 v1 = *(const u16x8*)&tile[wp][seg * 16 + 8];
        unsigned short* op = ln1 + (size_t)tok * DIM + chunk * 64 + seg * 16;
        *(u16x8*)op = v0;
        *(u16x8*)(op + 8) = v1;
        __syncthreads();
    }
}

// ---------------- MFMA GEMM: C[M,N] = A[M,K](bf16) * Bt[N,K]^T(bf16) + bias
// 128x128 tile, 4 waves, 4x4 16x16x32 MFMA.
// DIRECT global->register fragment loads (no K-loop LDS, no barriers):
// operands are L2/L3-resident (B <= 1.2MB, A panels re-read by neighbor
// blocks). Each fragment load inst = 16 rows x 64B full lines. Register
// double-buffer one K-step ahead covers L2 latency; waves fully decoupled.
// LDS used ONLY for the bf16 C-tile bounce (full-line coalesced stores).
// EPI: 0 bias->bf16; 1 bias+gelu->bf16; 2 bias+residual gather->f32;
//      3 bias->f32; 4 bias->bf16 scattered to [qkv][head][tok][48]
template <int EPI>
__global__ __launch_bounds__(256) void k_gemm_mfma(
        const unsigned short* __restrict__ A,
        const unsigned short* __restrict__ Bt,
        const float* __restrict__ bias,
        void* __restrict__ Cout,
        const float* __restrict__ xres,
        int N, int K, int GX) {
    __shared__ __align__(16) unsigned short SH[17408];   // C bounce [128][136]
    int tid  = threadIdx.x;
    int lane = tid & 63;
    int wave = tid >> 6;
    int wm = wave >> 1, wn = wave & 1;
    int quad = lane >> 4, l15 = lane & 15;

    int l   = blockIdx.x;
    int xcd = l & 7;
    int r_  = l >> 3;
    int bx  = r_ % GX;
    int by  = (r_ / GX) * 8 + xcd;
    int m0 = by * 128, n0 = bx * 128;

    // fragment base pointers: A row = m0+wm*64+r*16+l15, k = quad*8 (+32*t)
    const unsigned short* pa0 = A  + (size_t)(m0 + wm * 64 +  0 + l15) * K + quad * 8;
    const unsigned short* pa1 = A  + (size_t)(m0 + wm * 64 + 16 + l15) * K + quad * 8;
    const unsigned short* pa2 = A  + (size_t)(m0 + wm * 64 + 32 + l15) * K + quad * 8;
    const unsigned short* pa3 = A  + (size_t)(m0 + wm * 64 + 48 + l15) * K + quad * 8;
    const unsigned short* pb0 = Bt + (size_t)(n0 + wn * 64 +  0 + l15) * K + quad * 8;
    const unsigned short* pb1 = Bt + (size_t)(n0 + wn * 64 + 16 + l15) * K + quad * 8;
    const unsigned short* pb2 = Bt + (size_t)(n0 + wn * 64 + 32 + l15) * K + quad * 8;
    const unsigned short* pb3 = Bt + (size_t)(n0 + wn * 64 + 48 + l15) * K + quad * 8;

    f32x4 acc[4][4] = {};
    int nsteps = K >> 5;              // 12 or 48 here: always even

    // bank X = even steps, bank Y = odd steps (static names, rule #20)
    bf16x8 aX0 = *(const bf16x8*)pa0, aX1 = *(const bf16x8*)pa1;
    bf16x8 aX2 = *(const bf16x8*)pa2, aX3 = *(const bf16x8*)pa3;
    bf16x8 bX0 = *(const bf16x8*)pb0, bX1 = *(const bf16x8*)pb1;
    bf16x8 bX2 = *(const bf16x8*)pb2, bX3 = *(const bf16x8*)pb3;

    for (int t = 0; t < nsteps; t += 2) {
        int o1 = (t + 1) << 5;
        bf16x8 aY0 = *(const bf16x8*)(pa0 + o1), aY1 = *(const bf16x8*)(pa1 + o1);
        bf16x8 aY2 = *(const bf16x8*)(pa2 + o1), aY3 = *(const bf16x8*)(pa3 + o1);
        bf16x8 bY0 = *(const bf16x8*)(pb0 + o1), bY1 = *(const bf16x8*)(pb1 + o1);
        bf16x8 bY2 = *(const bf16x8*)(pb2 + o1), bY3 = *(const bf16x8*)(pb3 + o1);

        acc[0][0] = __builtin_amdgcn_mfma_f32_16x16x32_bf16(aX0, bX0, acc[0][0], 0, 0, 0);
        acc[0][1] = __builtin_amdgcn_mfma_f32_16x16x32_bf16(aX0, bX1, acc[0][1], 0, 0, 0);
        acc[0][2] = __builtin_amdgcn_mfma_f32_16x16x32_bf16(aX0, bX2, acc[0][2], 0, 0, 0);
        acc[0][3] = __builtin_amdgcn_mfma_f32_16x16x32_bf16(aX0, bX3, acc[0][3], 0, 0, 0);
        acc[1][0] = __builtin_amdgcn_mfma_f32_16x16x32_bf16(aX1, bX0, acc[1][0], 0, 0, 0);
        acc[1][1] = __builtin_amdgcn_mfma_f32_16x16x32_bf16(aX1, bX1, acc[1][1], 0, 0, 0);
        acc[1][2] = __builtin_amdgcn_mfma_f32_16x16x32_bf16(aX1, bX2, acc[1][2], 0, 0, 0);
        acc[1][3] = __builtin_amdgcn_mfma_f32_16x16x32_bf16(aX1, bX3, acc[1][3], 0, 0, 0);
        acc[2][0] = __builtin_amdgcn_mfma_f32_16x16x32_bf16(aX2, bX0, acc[2][0], 0, 0, 0);
        acc[2][1] = __builtin_amdgcn_mfma_f32_16x16x32_bf16(aX2, bX1, acc[2][1], 0, 0, 0);
        acc[2][2] = __builtin_amdgcn_mfma_f32_16x16x32_bf16(aX2, bX2, acc[2][2], 0, 0, 0);
        acc[2][3] = __builtin_amdgcn_mfma_f32_16x16x32_bf16(aX2, bX3, acc[2][3], 0, 0, 0);
        acc[3][0] = __builtin_amdgcn_mfma_f32_16x16x32_bf16(aX3, bX0, acc[3][0], 0, 0, 0);
        acc[3][1] = __builtin_amdgcn_mfma_f32_16x16x32_bf16(aX3, bX1, acc[3][1], 0, 0, 0);
        acc[3][2] = __builtin_amdgcn_mfma_f32_16x16x32_bf16(aX3, bX2, acc[3][2], 0, 0, 0);
        acc[3][3] = __builtin_amdgcn_mfma_f32_16x16x32_bf16(aX3, bX3, acc[3][3], 0, 0, 0);

        int o2 = (t + 2 < nsteps) ? (t + 2) << 5 : 0;   // clamped harmless load
        aX0 = *(const bf16x8*)(pa0 + o2); aX1 = *(const bf16x8*)(pa1 + o2);
        aX2 = *(const bf16x8*)(pa2 + o2); aX3 = *(const bf16x8*)(pa3 + o2);
        bX0 = *(const bf16x8*)(pb0 + o2); bX1 = *(const bf16x8*)(pb1 + o2);
        bX2 = *(const bf16x8*)(pb2 + o2); bX3 = *(const bf16x8*)(pb3 + o2);

        acc[0][0] = __builtin_amdgcn_mfma_f32_16x16x32_bf16(aY0, bY0, acc[0][0], 0, 0, 0);
        acc[0][1] = __builtin_amdgcn_mfma_f32_16x16x32_bf16(aY0, bY1, acc[0][1], 0, 0, 0);
        acc[0][2] = __builtin_amdgcn_mfma_f32_16x16x32_bf16(aY0, bY2, acc[0][2], 0, 0, 0);
        acc[0][3] = __builtin_amdgcn_mfma_f32_16x16x32_bf16(aY0, bY3, acc[0][3], 0, 0, 0);
        acc[1][0] = __builtin_amdgcn_mfma_f32_16x16x32_bf16(aY1, bY0, acc[1][0], 0, 0, 0);
        acc[1][1] = __builtin_amdgcn_mfma_f32_16x16x32_bf16(aY1, bY1, acc[1][1], 0, 0, 0);
        acc[1][2] = __builtin_amdgcn_mfma_f32_16x16x32_bf16(aY1, bY2, acc[1][2], 0, 0, 0);
        acc[1][3] = __builtin_amdgcn_mfma_f32_16x16x32_bf16(aY1, bY3, acc[1][3], 0, 0, 0);
        acc[2][0] = __builtin_amdgcn_mfma_f32_16x16x32_bf16(aY2, bY0, acc[2][0], 0, 0, 0);
        acc[2][1] = __builtin_amdgcn_mfma_f32_16x16x32_bf16(aY2, bY1, acc[2][1], 0, 0, 0);
        acc[2][2] = __builtin_amdgcn_mfma_f32_16x16x32_bf16(aY2, bY2, acc[2][2], 0, 0, 0);
        acc[2][3] = __builtin_amdgcn_mfma_f32_16x16x32_bf16(aY2, bY3, acc[2][3], 0, 0, 0);
        acc[3][0] = __builtin_amdgcn_mfma_f32_16x16x32_bf16(aY3, bY0, acc[3][0], 0, 0, 0);
        acc[3][1] = __builtin_amdgcn_mfma_f32_16x16x32_bf16(aY3, bY1, acc[3][1], 0, 0, 0);
        acc[3][2] = __builtin_amdgcn_mfma_f32_16x16x32_bf16(aY3, bY2, acc[3][2], 0, 0, 0);
        acc[3][3] = __builtin_amdgcn_mfma_f32_16x16x32_bf16(aY3, bY3, acc[3][3], 0, 0, 0);
    }

    if (EPI == 2 || EPI == 3) {
        // f32 outputs: 16 lanes x 4B = full 64B lines already
        #pragma unroll
        for (int r2 = 0; r2 < 4; r2++) {
            int n = n0 + wn * 64 + r2 * 16 + l15;
            float bn = bias[n];
            #pragma unroll
            for (int r = 0; r < 4; r++) {
                #pragma unroll
                for (int reg = 0; reg < 4; reg++) {
                    int m = m0 + wm * 64 + r * 16 + quad * 4 + reg;
                    float v = acc[r][r2][reg] + bn;
                    if (EPI == 2) {
                        int b, hs, ws_;
                        tok2src(m, b, hs, ws_);
                        v += xres[(((size_t)b * DIM + n) * 64 + hs) * 64 + ws_];
                    }
                    ((float*)Cout)[(size_t)m * N + n] = v;
                }
            }
        }
    } else {
        // bf16 outputs: bounce through LDS for full-line coalesced stores.
        #pragma unroll
        for (int r2 = 0; r2 < 4; r2++) {
            int col = wn * 64 + r2 * 16 + l15;
            float bn = bias[n0 + col];
            #pragma unroll
            for (int r = 0; r < 4; r++) {
                int row0 = wm * 64 + r * 16 + quad * 4;
                #pragma unroll
                for (int reg = 0; reg < 4; reg++) {
                    int row = row0 + reg;
                    float v = acc[r][r2][reg] + bn;
                    if (EPI == 1) v = gelu(v);
                    SH[(row * 136 + col) ^ (((row >> 3) & 1) << 4)] = f2bf(v);
                }
            }
        }
        __syncthreads();
        #pragma unroll
        for (int i = 0; i < 8; i++) {
            int chunk = tid + i * 256;        // [0, 2048)
            int m = chunk >> 4, nc = chunk & 15;
            int idx = (m * 136 + nc * 8) ^ (((m >> 3) & 1) << 4);
            u16x8 v = *(const u16x8*)&SH[idx];
            if (EPI == 4) {
                int n = n0 + nc * 8;
                int qi  = n / 384;
                int rem = n - qi * 384;
                int hh  = rem / 48;
                int d   = rem - hh * 48;      // 8-chunks never cross 48-boundary
                *(u16x8*)&((unsigned short*)Cout)[((size_t)(qi * 8 + hh) * NTOK + m0 + m) * 48 + d] = v;
            } else {
                *(u16x8*)&((unsigned short*)Cout)[(size_t)(m0 + m) * N + n0 + nc * 8] = v;
            }
        }
    }
}

// ---------------- MFMA attention: 1 block = 1 window, 4 waves x 2 heads -----
// qkvh layout: [qkv(3)][head(8)][tok(32768)][48] bf16.
__global__ __launch_bounds__(256) void k_attn_mfma(
        const unsigned short* __restrict__ qkvh,
        unsigned short* __restrict__ attn) {
    // per-wave LDS: VT [48][72] (3456 u16) + P [64][72] (4608 u16) = 8064 u16
    __shared__ __align__(16) unsigned short lds[4][8064];   // 64512 B total
    int tid  = threadIdx.x;
    int lane = tid & 63;
    int wave = tid >> 6;
    int quad = lane >> 4, l15 = lane & 15;
    int win  = blockIdx.x;
    int tok0 = win * 64;
    unsigned short* VT = &lds[wave][0];
    unsigned short* P  = &lds[wave][3456];
    const float scale = 0.14433756729740643f;  // 48^-0.5

    for (int hi = 0; hi < 2; hi++) {
        int h = wave + hi * 4;
        const unsigned short* qb = qkvh + ((size_t)(0 * 8 + h) * NTOK + tok0) * 48;
        const unsigned short* kb = qkvh + ((size_t)(1 * 8 + h) * NTOK + tok0) * 48;
        const unsigned short* vb = qkvh + ((size_t)(2 * 8 + h) * NTOK + tok0) * 48;

        // stage V^T into LDS: lane = token, write column `lane`
        #pragma unroll
        for (int i = 0; i < 6; i++) {
            u16x8 v = *(const u16x8*)&vb[lane * 48 + i * 8];
            #pragma unroll
            for (int j = 0; j < 8; j++)
                VT[(i * 8 + j) * 72 + lane] = v[j];
        }

        // K fragments (B-operand of QK^T): kf[ni][chunk]
        bf16x8 kf[4][2];
        #pragma unroll
        for (int ni = 0; ni < 4; ni++) {
            kf[ni][0] = *(const bf16x8*)&kb[(ni * 16 + l15) * 48 + quad * 8];
            bf16x8 z = {};
            if (quad < 2)
                z = *(const bf16x8*)&kb[(ni * 16 + l15) * 48 + 32 + quad * 8];
            kf[ni][1] = z;   // d in [48,64) zero-masked
        }

        // S = Q K^T   (64x64, K=48 padded to 64 with zeros)
        f32x4 sacc[4][4] = {};
        #pragma unroll
        for (int mi = 0; mi < 4; mi++) {
            bf16x8 qf0 = *(const bf16x8*)&qb[(mi * 16 + l15) * 48 + quad * 8];
            bf16x8 qf1 = {};
            if (quad < 2)
                qf1 = *(const bf16x8*)&qb[(mi * 16 + l15) * 48 + 32 + quad * 8];
            #pragma unroll
            for (int ni = 0; ni < 4; ni++) {
                sacc[mi][ni] = __builtin_amdgcn_mfma_f32_16x16x32_bf16(qf0, kf[ni][0], sacc[mi][ni], 0, 0, 0);
                sacc[mi][ni] = __builtin_amdgcn_mfma_f32_16x16x32_bf16(qf1, kf[ni][1], sacc[mi][ni], 0, 0, 0);
            }
        }

        // softmax over rows (C-layout: row=quad*4+reg, col=ni*16+l15), P -> LDS
        #pragma unroll
        for (int mi = 0; mi < 4; mi++) {
            #pragma unroll
            for (int reg = 0; reg < 4; reg++) {
                float s0 = sacc[mi][0][reg] * scale;
                float s1 = sacc[mi][1][reg] * scale;
                float s2 = sacc[mi][2][reg] * scale;
                float s3 = sacc[mi][3][reg] * scale;
                float mx = fmaxf(fmaxf(s0, s1), fmaxf(s2, s3));
                #pragma unroll
                for (int off = 1; off < 16; off <<= 1)
                    mx = fmaxf(mx, __shfl_xor(mx, off));
                float e0 = __expf(s0 - mx);
                float e1 = __expf(s1 - mx);
                float e2 = __expf(s2 - mx);
                float e3 = __expf(s3 - mx);
                float sm = e0 + e1 + e2 + e3;
                #pragma unroll
                for (int off = 1; off < 16; off <<= 1)
                    sm += __shfl_xor(sm, off);
                float inv = 1.0f / sm;
                int row = mi * 16 + quad * 4 + reg;
                P[row * 72 +  0 + l15] = f2bf(e0 * inv);
                P[row * 72 + 16 + l15] = f2bf(e1 * inv);
                P[row * 72 + 32 + l15] = f2bf(e2 * inv);
                P[row * 72 + 48 + l15] = f2bf(e3 * inv);
            }
        }

        // O = P V   (64x48, K=64); V^T fragments from LDS
        bf16x8 vf[3][2];
        #pragma unroll
        for (int ni = 0; ni < 3; ni++)
            #pragma unroll
            for (int kt = 0; kt < 2; kt++)
                vf[ni][kt] = *(const bf16x8*)&VT[(ni * 16 + l15) * 72 + kt * 32 + quad * 8];

        #pragma unroll
        for (int mi = 0; mi < 4; mi++) {
            bf16x8 pf0 = *(const bf16x8*)&P[(mi * 16 + l15) * 72 + quad * 8];
            bf16x8 pf1 = *(const bf16x8*)&P[(mi * 16 + l15) * 72 + 32 + quad * 8];
            f32x4 o[3] = {};
            #pragma unroll
            for (int ni = 0; ni < 3; ni++) {
                o[ni] = __builtin_amdgcn_mfma_f32_16x16x32_bf16(pf0, vf[ni][0], o[ni], 0, 0, 0);
                o[ni] = __builtin_amdgcn_mfma_f32_16x16x32_bf16(pf1, vf[ni][1], o[ni], 0, 0, 0);
            }
            #pragma unroll
            for (int ni = 0; ni < 3; ni++)
                #pragma unroll
                for (int reg = 0; reg < 4; reg++) {
                    int tok = tok0 + mi * 16 + quad * 4 + reg;
                    attn[(size_t)tok * DIM + h * HD + ni * 16 + l15] = f2bf(o[ni][reg]);
                }
        }
    }
}

// ---------------- LayerNorm2 over y (f32) -> ln2 (bf16) ----------
__global__ __launch_bounds__(64) void k_ln2(const float* __restrict__ y,
                                            const float* __restrict__ g,
                                            const float* __restrict__ bt,
                                            unsigned short* __restrict__ out) {
    int tok = blockIdx.x;
    int t   = threadIdx.x;
    const float* row = y + (size_t)tok * DIM;
    float v[6];
    float sum = 0.f, sq = 0.f;
    #pragma unroll
    for (int i = 0; i < 6; i++) {
        v[i] = row[i * 64 + t];
        sum += v[i]; sq += v[i] * v[i];
    }
    #pragma unroll
    for (int o = 32; o > 0; o >>= 1) {
        sum += __shfl_xor(sum, o, 64);
        sq  += __shfl_xor(sq, o, 64);
    }
    float mean = sum * (1.0f / DIM);
    float var  = sq * (1.0f / DIM) - mean * mean;
    float rstd = rsqrtf(var + 1e-5f);
    unsigned short* orow = out + (size_t)tok * DIM;
    #pragma unroll
    for (int i = 0; i < 6; i++) {
        int c = i * 64 + t;
        orow[c] = f2bf((v[i] - mean) * rstd * g[c] + bt[c]);
    }
}

// ---------------- un-permute + transpose to [B,C,H,W] ------------
__global__ __launch_bounds__(256) void k_out(const float* __restrict__ hbuf,
                                             float* __restrict__ out) {
    int bh = blockIdx.x;
    int b = bh >> 6, h = bh & 63;
    int t = threadIdx.x;
    __shared__ float T[64][193];
    int hh = (h + 60) & 63;
    int hi = hh >> 3, r = hh & 7;
    for (int half = 0; half < 2; half++) {
        int c0 = half * 192;
        for (int idx = t; idx < 64 * 192; idx += 256) {
            int w = idx / 192;
            int c = idx - w * 192;
            int ww = (w + 60) & 63;
            int wi = ww >> 3, cc2 = ww & 7;
            int tok = ((b * 8 + hi) * 8 + wi) * 64 + r * 8 + cc2;
            T[w][c] = hbuf[(size_t)tok * DIM + c0 + c];
        }
        __syncthreads();
        for (int idx = t; idx < 64 * 192; idx += 256) {
            int cc = idx >> 6;
            int w  = idx & 63;
            out[(((size_t)b * DIM + c0 + cc) * 64 + h) * 64 + w] = T[w][cc];
        }
        __syncthreads();
    }
}

extern "C" void kernel_launch(void* const* d_in, const int* in_sizes, int n_in,
                              void* d_out, int out_size, void* d_ws, size_t ws_size,
                              hipStream_t stream) {
    const float* x      = (const float*)d_in[0];
    const float* qkv_w  = (const float*)d_in[1];
    const float* qkv_b  = (const float*)d_in[2];
    const float* proj_w = (const float*)d_in[3];
    const float* proj_b = (const float*)d_in[4];
    const float* ln1_g  = (const float*)d_in[5];
    const float* ln1_b  = (const float*)d_in[6];
    const float* ln2_g  = (const float*)d_in[7];
    const float* ln2_b  = (const float*)d_in[8];
    const float* w1     = (const float*)d_in[9];
    const float* b1     = (const float*)d_in[10];
    const float* w2     = (const float*)d_in[11];
    const float* b2     = (const float*)d_in[12];

    char* ws = (char*)d_ws;
    unsigned short* qkv_wt  = (unsigned short*)(ws + 0);
    unsigned short* proj_wt = (unsigned short*)(ws + 884736);
    unsigned short* w1t     = (unsigned short*)(ws + 1179648);
    unsigned short* w2t     = (unsigned short*)(ws + 2359296);
    unsigned short* ln1     = (unsigned short*)(ws + 4194304);
    unsigned short* qkv     = (unsigned short*)(ws + 29360128);   // [3][8][32768][48]
    unsigned short* attn    = (unsigned short*)(ws + 104857600);
    float*          y       = (float*)(ws + 130023424);
    unsigned short* ln2     = ln1;
    unsigned short* mid     = qkv;      // [32768][1536] bf16
    float*          hbuf    = y;

    k_wt4<<<6912, 256, 0, stream>>>(qkv_w, proj_w, w1, w2, qkv_wt, proj_wt, w1t, w2t);
    k_ln1<<<512, 256, 0, stream>>>(x, ln1_g, ln1_b, ln1);
    k_gemm_mfma<4><<<9 * 256, 256, 0, stream>>>(ln1, qkv_wt, qkv_b, qkv, nullptr, 1152, 384, 9);
    k_attn_mfma<<<NWIN, 256, 0, stream>>>(qkv, attn);
    k_gemm_mfma<2><<<3 * 256, 256, 0, stream>>>(attn, proj_wt, proj_b, y, x, 384, 384, 3);
    k_ln2<<<NTOK, 64, 0, stream>>>(y, ln2_g, ln2_b, ln2);
    k_gemm_mfma<1><<<12 * 256, 256, 0, stream>>>(ln2, w1t, b1, mid, nullptr, 1536, 384, 12);
    k_gemm_mfma<3><<<3 * 256, 256, 0, stream>>>(mid, w2t, b2, hbuf, nullptr, 384, 1536, 3);
    k_out<<<NWIN, 256, 0, stream>>>(hbuf, (float*)d_out);
}

// Round 5
// 556.358 us; speedup vs baseline: 1.2443x; 1.2443x over previous
//
#include <hip/hip_runtime.h>
#include <hip/hip_bf16.h>
#include <math.h>

#define DIM   384
#define HEADS 8
#define HD    48
#define NTOK  32768   // 8 * 64 * 64
#define NWIN  512     // 8 images * 64 windows

typedef __attribute__((ext_vector_type(8))) short bf16x8;
typedef __attribute__((ext_vector_type(8))) unsigned short u16x8;
typedef __attribute__((ext_vector_type(4))) float f32x4;

__device__ __forceinline__ float bf2f(unsigned short u) {
    unsigned int v = ((unsigned int)u) << 16;
    return __uint_as_float(v);
}
// RNE f32->bf16 via native cast (v_cvt_pk_bf16_f32 on gfx950)
__device__ __forceinline__ unsigned short f2bf(float f) {
    __bf16 b = (__bf16)f;
    return __builtin_bit_cast(unsigned short, b);
}

// branchless erf-based GELU (A&S 7.1.25 3-term, |err_erf| < 2.5e-5 << bf16 ulp)
__device__ __forceinline__ float gelu(float v) {
    float z  = v * 0.70710678118654752f;
    float az = fabsf(z);
    float t  = __builtin_amdgcn_rcpf(1.0f + 0.47047f * az);
    float p  = t * (0.3480242f + t * (-0.0958798f + t * 0.7478556f));
    float ea = 1.0f - p * __expf(-az * az);
    float er = copysignf(ea, z);
    return 0.5f * v * (1.0f + er);
}

// token (window order) -> source pixel of x (accounting for roll by -SHIFT)
__device__ __forceinline__ void tok2src(int tok, int& b, int& hs, int& ws) {
    int bb  = tok >> 12;
    int win = (tok >> 6) & 63;
    int t   = tok & 63;
    int hi = win >> 3, wi = win & 7;
    int r  = t >> 3,  cc = t & 7;
    b  = bb;
    hs = (hi * 8 + r  + 4) & 63;
    ws = (wi * 8 + cc + 4) & 63;
}

// ------------- weight convert f32 [K][N] -> bf16 [N][K], coalesced both
// sides via 64x64 LDS tile transpose. One block = one 64x64 tile.
__global__ __launch_bounds__(256) void k_wt4(const float* __restrict__ qkv_w,
                                             const float* __restrict__ proj_w,
                                             const float* __restrict__ w1,
                                             const float* __restrict__ w2,
                                             unsigned short* __restrict__ d0,
                                             unsigned short* __restrict__ d1,
                                             unsigned short* __restrict__ d2,
                                             unsigned short* __restrict__ d3) {
    // tiles: qkv 6x18=108 | proj 6x6=36 | w1 6x24=144 | w2 24x6=144  => 432
    __shared__ unsigned short T[64][66];
    int b = blockIdx.x;
    const float* W; unsigned short* Wt; int K, N, lt;
    if (b < 108)      { W = qkv_w;  Wt = d0; K = 384;  N = 1152; lt = b; }
    else if (b < 144) { W = proj_w; Wt = d1; K = 384;  N = 384;  lt = b - 108; }
    else if (b < 288) { W = w1;     Wt = d2; K = 384;  N = 1536; lt = b - 144; }
    else              { W = w2;     Wt = d3; K = 1536; N = 384;  lt = b - 288; }
    int tn = N >> 6;
    int k0 = (lt / tn) << 6, n0 = (lt % tn) << 6;
    int t  = threadIdx.x;
    int cl = t & 63, rw = t >> 6;
    #pragma unroll
    for (int p = 0; p < 16; p++) {
        int kk = p * 4 + rw;
        T[cl][kk] = f2bf(W[(size_t)(k0 + kk) * N + n0 + cl]);  // coalesced in n
    }
    __syncthreads();
    #pragma unroll
    for (int p = 0; p < 16; p++) {
        int nn = p * 4 + rw;
        Wt[(size_t)(n0 + nn) * K + k0 + cl] = T[nn][cl];       // coalesced in k
    }
}

// -------- gather + LayerNorm1, per (b, image-row hs), coalesced ------------
__global__ __launch_bounds__(256) void k_ln1(const float* __restrict__ x,
                                             const float* __restrict__ g,
                                             const float* __restrict__ bt,
                                             unsigned short* __restrict__ ln1) {
    int blk = blockIdx.x;           // b*64 + hs
    int b  = blk >> 6, hs = blk & 63;
    int t  = threadIdx.x;
    int w  = t & 63, cg = t >> 6;   // pixel, channel-group (4)
    const float* row = x + (size_t)b * DIM * 4096 + hs * 64;

    float sum = 0.f, sq = 0.f;
    for (int i = 0; i < 96; i++) {
        int c = i * 4 + cg;
        float v = row[(size_t)c * 4096 + w];
        sum += v; sq += v * v;
    }
    __shared__ float red[2][4][64];
    __shared__ float mean_s[64], rstd_s[64];
    red[0][cg][w] = sum; red[1][cg][w] = sq;
    __syncthreads();
    if (t < 64) {
        float s  = red[0][0][t] + red[0][1][t] + red[0][2][t] + red[0][3][t];
        float q2 = red[1][0][t] + red[1][1][t] + red[1][2][t] + red[1][3][t];
        float mean = s * (1.0f / DIM);
        float var  = q2 * (1.0f / DIM) - mean * mean;
        mean_s[t] = mean;
        rstd_s[t] = rsqrtf(var + 1e-5f);
    }
    __syncthreads();

    int wp = t >> 2, seg = t & 3;
    int hr = (hs + 60) & 63, wr = (wp + 60) & 63;
    int tok = ((b * 8 + (hr >> 3)) * 8 + (wr >> 3)) * 64 + (hr & 7) * 8 + (wr & 7);

    __shared__ __align__(16) unsigned short tile[64][72];
    for (int chunk = 0; chunk < 6; chunk++) {
        float mean = mean_s[w], rstd = rstd_s[w];
        #pragma unroll
        for (int it = 0; it < 16; it++) {
            int cl = it * 4 + cg;
            int c  = chunk * 64 + cl;
            float v = row[(size_t)c * 4096 + w];
            tile[w][cl] = f2bf((v - mean) * rstd * g[c] + bt[c]);
        }
        __syncthreads();
        u16x8 v0 = *(const u16x8*)&tile[wp][seg * 16];
        u16x8 v1 = *(const u16x8*)&tile[wp][seg * 16 + 8];
        unsigned short* op = ln1 + (size_t)tok * DIM + chunk * 64 + seg * 16;
        *(u16x8*)op = v0;
        *(u16x8*)(op + 8) = v1;
        __syncthreads();
    }
}

// ---------------- MFMA GEMM: C[M,N] = A[M,K](bf16) * Bt[N,K]^T(bf16) + bias
// 128x128 tile, 4 waves, 4x4 16x16x32 MFMA, BK=32 single-buffered staging.
// LDS = 17.4 KB only (staging 16 KB unioned with half-tile C bounce) =>
// ~6 blocks/CU residency; cross-block TLP hides barrier/load stalls
// (pipelining depth 0/1/2 all measured equal; residency was the binder).
// bf16 epilogues (EPI 0/1/4) bounce C through LDS in 2 wave-pair phases
// so all HBM writes are full-line u16x8.
// EPI: 0 bias->bf16; 1 bias+gelu->bf16; 2 bias+residual gather->f32;
//      3 bias->f32; 4 bias->bf16 scattered to [qkv][head][tok][48]
template <int EPI>
__global__ __launch_bounds__(256) void k_gemm_mfma(
        const unsigned short* __restrict__ A,
        const unsigned short* __restrict__ Bt,
        const float* __restrict__ bias,
        void* __restrict__ Cout,
        const float* __restrict__ xres,
        int N, int K, int GX) {
    // staging: A [0,4096) u16, B [4096,8192) u16.
    // bounce (bf16 EPIs, after K-loop): [64][136] u16 = 8704 u16, reuses SH.
    __shared__ __align__(16) unsigned short SH[8704];   // 17408 B
    int tid  = threadIdx.x;
    int lane = tid & 63;
    int wave = tid >> 6;
    int wm = wave >> 1, wn = wave & 1;
    int quad = lane >> 4, l15 = lane & 15;

    int l   = blockIdx.x;
    int xcd = l & 7;
    int r_  = l >> 3;
    int bx  = r_ % GX;
    int by  = (r_ / GX) * 8 + xcd;
    int m0 = by * 128, n0 = bx * 128;

    const unsigned short* gA0 = A  + (size_t)(m0 +      lane) * K + wave * 8;
    const unsigned short* gA1 = A  + (size_t)(m0 + 64 + lane) * K + wave * 8;
    const unsigned short* gB0 = Bt + (size_t)(n0 +      lane) * K + wave * 8;
    const unsigned short* gB1 = Bt + (size_t)(n0 + 64 + lane) * K + wave * 8;

    f32x4 acc[4][4] = {};
    int nsteps = K >> 5;

    for (int t = 0; t < nsteps; ++t) {
        // prev trailing barrier guarantees all waves done reading SH
        __builtin_amdgcn_global_load_lds(
            (const __attribute__((address_space(1))) void*)gA0,
            (__attribute__((address_space(3))) void*)&SH[wave * 1024],
            16, 0, 0);
        __builtin_amdgcn_global_load_lds(
            (const __attribute__((address_space(1))) void*)gA1,
            (__attribute__((address_space(3))) void*)&SH[wave * 1024 + 512],
            16, 0, 0);
        __builtin_amdgcn_global_load_lds(
            (const __attribute__((address_space(1))) void*)gB0,
            (__attribute__((address_space(3))) void*)&SH[4096 + wave * 1024],
            16, 0, 0);
        __builtin_amdgcn_global_load_lds(
            (const __attribute__((address_space(1))) void*)gB1,
            (__attribute__((address_space(3))) void*)&SH[4096 + wave * 1024 + 512],
            16, 0, 0);
        gA0 += 32; gA1 += 32; gB0 += 32; gB1 += 32;
        __syncthreads();   // drains vmcnt(0): all waves' stage visible

        bf16x8 af[4], bfr[4];
        #pragma unroll
        for (int r = 0; r < 4; r++)
            af[r] = *(const bf16x8*)&SH[(quad * 128 + wm * 64 + r * 16 + l15) * 8];
        #pragma unroll
        for (int r2 = 0; r2 < 4; r2++)
            bfr[r2] = *(const bf16x8*)&SH[4096 + (quad * 128 + wn * 64 + r2 * 16 + l15) * 8];
        #pragma unroll
        for (int r = 0; r < 4; r++)
            #pragma unroll
            for (int r2 = 0; r2 < 4; r2++)
                acc[r][r2] = __builtin_amdgcn_mfma_f32_16x16x32_bf16(
                                 af[r], bfr[r2], acc[r][r2], 0, 0, 0);
        __syncthreads();   // all waves done reading; next stage may overwrite
    }

    if (EPI == 2 || EPI == 3) {
        // f32 outputs: 16 lanes x 4B = full 64B lines already
        #pragma unroll
        for (int r2 = 0; r2 < 4; r2++) {
            int n = n0 + wn * 64 + r2 * 16 + l15;
            float bn = bias[n];
            #pragma unroll
            for (int r = 0; r < 4; r++) {
                #pragma unroll
                for (int reg = 0; reg < 4; reg++) {
                    int m = m0 + wm * 64 + r * 16 + quad * 4 + reg;
                    float v = acc[r][r2][reg] + bn;
                    if (EPI == 2) {
                        int b, hs, ws_;
                        tok2src(m, b, hs, ws_);
                        v += xres[(((size_t)b * DIM + n) * 64 + hs) * 64 + ws_];
                    }
                    ((float*)Cout)[(size_t)m * N + n] = v;
                }
            }
        }
    } else {
        // bf16 outputs: 2-phase bounce. Rows 0-63 live entirely in waves
        // wm==0, rows 64-127 in wm==1 -> wave-pair writes, all waves read.
        #pragma unroll
        for (int half = 0; half < 2; half++) {
            if (wm == half) {
                #pragma unroll
                for (int r2 = 0; r2 < 4; r2++) {
                    int col = wn * 64 + r2 * 16 + l15;
                    float bn = bias[n0 + col];
                    #pragma unroll
                    for (int r = 0; r < 4; r++) {
                        int row0 = r * 16 + quad * 4;
                        #pragma unroll
                        for (int reg = 0; reg < 4; reg++) {
                            int row = row0 + reg;     // local row in [0,64)
                            float v = acc[r][r2][reg] + bn;
                            if (EPI == 1) v = gelu(v);
                            SH[(row * 136 + col) ^ (((row >> 3) & 1) << 4)] = f2bf(v);
                        }
                    }
                }
            }
            __syncthreads();
            #pragma unroll
            for (int i = 0; i < 4; i++) {
                int chunk = tid + i * 256;        // [0, 1024)
                int ml = chunk >> 4, nc = chunk & 15;
                int idx = (ml * 136 + nc * 8) ^ (((ml >> 3) & 1) << 4);
                u16x8 v = *(const u16x8*)&SH[idx];
                int m = m0 + half * 64 + ml;
                if (EPI == 4) {
                    int n = n0 + nc * 8;
                    int qi  = n / 384;
                    int rem = n - qi * 384;
                    int hh  = rem / 48;
                    int d   = rem - hh * 48;      // 8-chunks never cross 48-boundary
                    *(u16x8*)&((unsigned short*)Cout)[((size_t)(qi * 8 + hh) * NTOK + m) * 48 + d] = v;
                } else {
                    *(u16x8*)&((unsigned short*)Cout)[(size_t)m * N + n0 + nc * 8] = v;
                }
            }
            __syncthreads();
        }
    }
}

// ---------------- MFMA attention: 1 block = 1 window, 4 waves x 2 heads -----
// qkvh layout: [qkv(3)][head(8)][tok(32768)][48] bf16.
__global__ __launch_bounds__(256) void k_attn_mfma(
        const unsigned short* __restrict__ qkvh,
        unsigned short* __restrict__ attn) {
    // per-wave LDS: VT [48][72] (3456 u16) + P [64][72] (4608 u16) = 8064 u16
    __shared__ __align__(16) unsigned short lds[4][8064];   // 64512 B total
    int tid  = threadIdx.x;
    int lane = tid & 63;
    int wave = tid >> 6;
    int quad = lane >> 4, l15 = lane & 15;
    int win  = blockIdx.x;
    int tok0 = win * 64;
    unsigned short* VT = &lds[wave][0];
    unsigned short* P  = &lds[wave][3456];
    const float scale = 0.14433756729740643f;  // 48^-0.5

    for (int hi = 0; hi < 2; hi++) {
        int h = wave + hi * 4;
        const unsigned short* qb = qkvh + ((size_t)(0 * 8 + h) * NTOK + tok0) * 48;
        const unsigned short* kb = qkvh + ((size_t)(1 * 8 + h) * NTOK + tok0) * 48;
        const unsigned short* vb = qkvh + ((size_t)(2 * 8 + h) * NTOK + tok0) * 48;

        // stage V^T into LDS: lane = token, write column `lane`
        #pragma unroll
        for (int i = 0; i < 6; i++) {
            u16x8 v = *(const u16x8*)&vb[lane * 48 + i * 8];
            #pragma unroll
            for (int j = 0; j < 8; j++)
                VT[(i * 8 + j) * 72 + lane] = v[j];
        }

        // K fragments (B-operand of QK^T): kf[ni][chunk]
        bf16x8 kf[4][2];
        #pragma unroll
        for (int ni = 0; ni < 4; ni++) {
            kf[ni][0] = *(const bf16x8*)&kb[(ni * 16 + l15) * 48 + quad * 8];
            bf16x8 z = {};
            if (quad < 2)
                z = *(const bf16x8*)&kb[(ni * 16 + l15) * 48 + 32 + quad * 8];
            kf[ni][1] = z;   // d in [48,64) zero-masked
        }

        // S = Q K^T   (64x64, K=48 padded to 64 with zeros)
        f32x4 sacc[4][4] = {};
        #pragma unroll
        for (int mi = 0; mi < 4; mi++) {
            bf16x8 qf0 = *(const bf16x8*)&qb[(mi * 16 + l15) * 48 + quad * 8];
            bf16x8 qf1 = {};
            if (quad < 2)
                qf1 = *(const bf16x8*)&qb[(mi * 16 + l15) * 48 + 32 + quad * 8];
            #pragma unroll
            for (int ni = 0; ni < 4; ni++) {
                sacc[mi][ni] = __builtin_amdgcn_mfma_f32_16x16x32_bf16(qf0, kf[ni][0], sacc[mi][ni], 0, 0, 0);
                sacc[mi][ni] = __builtin_amdgcn_mfma_f32_16x16x32_bf16(qf1, kf[ni][1], sacc[mi][ni], 0, 0, 0);
            }
        }

        // softmax over rows (C-layout: row=quad*4+reg, col=ni*16+l15), P -> LDS
        #pragma unroll
        for (int mi = 0; mi < 4; mi++) {
            #pragma unroll
            for (int reg = 0; reg < 4; reg++) {
                float s0 = sacc[mi][0][reg] * scale;
                float s1 = sacc[mi][1][reg] * scale;
                float s2 = sacc[mi][2][reg] * scale;
                float s3 = sacc[mi][3][reg] * scale;
                float mx = fmaxf(fmaxf(s0, s1), fmaxf(s2, s3));
                #pragma unroll
                for (int off = 1; off < 16; off <<= 1)
                    mx = fmaxf(mx, __shfl_xor(mx, off));
                float e0 = __expf(s0 - mx);
                float e1 = __expf(s1 - mx);
                float e2 = __expf(s2 - mx);
                float e3 = __expf(s3 - mx);
                float sm = e0 + e1 + e2 + e3;
                #pragma unroll
                for (int off = 1; off < 16; off <<= 1)
                    sm += __shfl_xor(sm, off);
                float inv = 1.0f / sm;
                int row = mi * 16 + quad * 4 + reg;
                P[row * 72 +  0 + l15] = f2bf(e0 * inv);
                P[row * 72 + 16 + l15] = f2bf(e1 * inv);
                P[row * 72 + 32 + l15] = f2bf(e2 * inv);
                P[row * 72 + 48 + l15] = f2bf(e3 * inv);
            }
        }

        // O = P V   (64x48, K=64); V^T fragments from LDS
        bf16x8 vf[3][2];
        #pragma unroll
        for (int ni = 0; ni < 3; ni++)
            #pragma unroll
            for (int kt = 0; kt < 2; kt++)
                vf[ni][kt] = *(const bf16x8*)&VT[(ni * 16 + l15) * 72 + kt * 32 + quad * 8];

        #pragma unroll
        for (int mi = 0; mi < 4; mi++) {
            bf16x8 pf0 = *(const bf16x8*)&P[(mi * 16 + l15) * 72 + quad * 8];
            bf16x8 pf1 = *(const bf16x8*)&P[(mi * 16 + l15) * 72 + 32 + quad * 8];
            f32x4 o[3] = {};
            #pragma unroll
            for (int ni = 0; ni < 3; ni++) {
                o[ni] = __builtin_amdgcn_mfma_f32_16x16x32_bf16(pf0, vf[ni][0], o[ni], 0, 0, 0);
                o[ni] = __builtin_amdgcn_mfma_f32_16x16x32_bf16(pf1, vf[ni][1], o[ni], 0, 0, 0);
            }
            #pragma unroll
            for (int ni = 0; ni < 3; ni++)
                #pragma unroll
                for (int reg = 0; reg < 4; reg++) {
                    int tok = tok0 + mi * 16 + quad * 4 + reg;
                    attn[(size_t)tok * DIM + h * HD + ni * 16 + l15] = f2bf(o[ni][reg]);
                }
        }
    }
}

// ---------------- LayerNorm2 over y (f32) -> ln2 (bf16) ----------
__global__ __launch_bounds__(64) void k_ln2(const float* __restrict__ y,
                                            const float* __restrict__ g,
                                            const float* __restrict__ bt,
                                            unsigned short* __restrict__ out) {
    int tok = blockIdx.x;
    int t   = threadIdx.x;
    const float* row = y + (size_t)tok * DIM;
    float v[6];
    float sum = 0.f, sq = 0.f;
    #pragma unroll
    for (int i = 0; i < 6; i++) {
        v[i] = row[i * 64 + t];
        sum += v[i]; sq += v[i] * v[i];
    }
    #pragma unroll
    for (int o = 32; o > 0; o >>= 1) {
        sum += __shfl_xor(sum, o, 64);
        sq  += __shfl_xor(sq, o, 64);
    }
    float mean = sum * (1.0f / DIM);
    float var  = sq * (1.0f / DIM) - mean * mean;
    float rstd = rsqrtf(var + 1e-5f);
    unsigned short* orow = out + (size_t)tok * DIM;
    #pragma unroll
    for (int i = 0; i < 6; i++) {
        int c = i * 64 + t;
        orow[c] = f2bf((v[i] - mean) * rstd * g[c] + bt[c]);
    }
}

// ---------------- un-permute + transpose to [B,C,H,W] ------------
__global__ __launch_bounds__(256) void k_out(const float* __restrict__ hbuf,
                                             float* __restrict__ out) {
    int bh = blockIdx.x;
    int b = bh >> 6, h = bh & 63;
    int t = threadIdx.x;
    __shared__ float T[64][193];
    int hh = (h + 60) & 63;
    int hi = hh >> 3, r = hh & 7;
    for (int half = 0; half < 2; half++) {
        int c0 = half * 192;
        for (int idx = t; idx < 64 * 192; idx += 256) {
            int w = idx / 192;
            int c = idx - w * 192;
            int ww = (w + 60) & 63;
            int wi = ww >> 3, cc2 = ww & 7;
            int tok = ((b * 8 + hi) * 8 + wi) * 64 + r * 8 + cc2;
            T[w][c] = hbuf[(size_t)tok * DIM + c0 + c];
        }
        __syncthreads();
        for (int idx = t; idx < 64 * 192; idx += 256) {
            int cc = idx >> 6;
            int w  = idx & 63;
            out[(((size_t)b * DIM + c0 + cc) * 64 + h) * 64 + w] = T[w][cc];
        }
        __syncthreads();
    }
}

extern "C" void kernel_launch(void* const* d_in, const int* in_sizes, int n_in,
                              void* d_out, int out_size, void* d_ws, size_t ws_size,
                              hipStream_t stream) {
    const float* x      = (const float*)d_in[0];
    const float* qkv_w  = (const float*)d_in[1];
    const float* qkv_b  = (const float*)d_in[2];
    const float* proj_w = (const float*)d_in[3];
    const float* proj_b = (const float*)d_in[4];
    const float* ln1_g  = (const float*)d_in[5];
    const float* ln1_b  = (const float*)d_in[6];
    const float* ln2_g  = (const float*)d_in[7];
    const float* ln2_b  = (const float*)d_in[8];
    const float* w1     = (const float*)d_in[9];
    const float* b1     = (const float*)d_in[10];
    const float* w2     = (const float*)d_in[11];
    const float* b2     = (const float*)d_in[12];

    char* ws = (char*)d_ws;
    unsigned short* qkv_wt  = (unsigned short*)(ws + 0);
    unsigned short* proj_wt = (unsigned short*)(ws + 884736);
    unsigned short* w1t     = (unsigned short*)(ws + 1179648);
    unsigned short* w2t     = (unsigned short*)(ws + 2359296);
    unsigned short* ln1     = (unsigned short*)(ws + 4194304);
    unsigned short* qkv     = (unsigned short*)(ws + 29360128);   // [3][8][32768][48]
    unsigned short* attn    = (unsigned short*)(ws + 104857600);
    float*          y       = (float*)(ws + 130023424);
    unsigned short* ln2     = ln1;
    unsigned short* mid     = qkv;      // [32768][1536] bf16
    float*          hbuf    = y;

    k_wt4<<<432, 256, 0, stream>>>(qkv_w, proj_w, w1, w2, qkv_wt, proj_wt, w1t, w2t);
    k_ln1<<<512, 256, 0, stream>>>(x, ln1_g, ln1_b, ln1);
    k_gemm_mfma<4><<<9 * 256, 256, 0, stream>>>(ln1, qkv_wt, qkv_b, qkv, nullptr, 1152, 384, 9);
    k_attn_mfma<<<NWIN, 256, 0, stream>>>(qkv, attn);
    k_gemm_mfma<2><<<3 * 256, 256, 0, stream>>>(attn, proj_wt, proj_b, y, x, 384, 384, 3);
    k_ln2<<<NTOK, 64, 0, stream>>>(y, ln2_g, ln2_b, ln2);
    k_gemm_mfma<1><<<12 * 256, 256, 0, stream>>>(ln2, w1t, b1, mid, nullptr, 1536, 384, 12);
    k_gemm_mfma<3><<<3 * 256, 256, 0, stream>>>(mid, w2t, b2, hbuf, nullptr, 384, 1536, 3);
    k_out<<<NWIN, 256, 0, stream>>>(hbuf, (float*)d_out);
}

// Round 6
// 488.469 us; speedup vs baseline: 1.4173x; 1.1390x over previous
//
#include <hip/hip_runtime.h>
#include <hip/hip_bf16.h>
#include <math.h>

#define DIM   384
#define HEADS 8
#define HD    48
#define NTOK  32768   // 8 * 64 * 64
#define NWIN  512     // 8 images * 64 windows

typedef __attribute__((ext_vector_type(8))) short bf16x8;
typedef __attribute__((ext_vector_type(8))) unsigned short u16x8;
typedef __attribute__((ext_vector_type(4))) float f32x4;

__device__ __forceinline__ float bf2f(unsigned short u) {
    unsigned int v = ((unsigned int)u) << 16;
    return __uint_as_float(v);
}
// RNE f32->bf16 via native cast (proven bit-identical in R5 bench)
__device__ __forceinline__ unsigned short f2bf(float f) {
    __bf16 b = (__bf16)f;
    return __builtin_bit_cast(unsigned short, b);
}

// branchless erf-based GELU (A&S 7.1.25 3-term, |err_erf| < 2.5e-5 << bf16 ulp)
__device__ __forceinline__ float gelu(float v) {
    float z  = v * 0.70710678118654752f;
    float az = fabsf(z);
    float t  = __builtin_amdgcn_rcpf(1.0f + 0.47047f * az);
    float p  = t * (0.3480242f + t * (-0.0958798f + t * 0.7478556f));
    float ea = 1.0f - p * __expf(-az * az);
    float er = copysignf(ea, z);
    return 0.5f * v * (1.0f + er);
}

// token (window order) -> source pixel of x (accounting for roll by -SHIFT)
__device__ __forceinline__ void tok2src(int tok, int& b, int& hs, int& ws) {
    int bb  = tok >> 12;
    int win = (tok >> 6) & 63;
    int t   = tok & 63;
    int hi = win >> 3, wi = win & 7;
    int r  = t >> 3,  cc = t & 7;
    b  = bb;
    hs = (hi * 8 + r  + 4) & 63;
    ws = (wi * 8 + cc + 4) & 63;
}

// ------------- weight convert f32 [K][N] -> bf16 [N][K], coalesced both
// sides via 64x64 LDS tile transpose. One block = one 64x64 tile.
__global__ __launch_bounds__(256) void k_wt4(const float* __restrict__ qkv_w,
                                             const float* __restrict__ proj_w,
                                             const float* __restrict__ w1,
                                             const float* __restrict__ w2,
                                             unsigned short* __restrict__ d0,
                                             unsigned short* __restrict__ d1,
                                             unsigned short* __restrict__ d2,
                                             unsigned short* __restrict__ d3) {
    // tiles: qkv 6x18=108 | proj 6x6=36 | w1 6x24=144 | w2 24x6=144  => 432
    __shared__ unsigned short T[64][66];
    int b = blockIdx.x;
    const float* W; unsigned short* Wt; int K, N, lt;
    if (b < 108)      { W = qkv_w;  Wt = d0; K = 384;  N = 1152; lt = b; }
    else if (b < 144) { W = proj_w; Wt = d1; K = 384;  N = 384;  lt = b - 108; }
    else if (b < 288) { W = w1;     Wt = d2; K = 384;  N = 1536; lt = b - 144; }
    else              { W = w2;     Wt = d3; K = 1536; N = 384;  lt = b - 288; }
    int tn = N >> 6;
    int k0 = (lt / tn) << 6, n0 = (lt % tn) << 6;
    int t  = threadIdx.x;
    int cl = t & 63, rw = t >> 6;
    #pragma unroll
    for (int p = 0; p < 16; p++) {
        int kk = p * 4 + rw;
        T[cl][kk] = f2bf(W[(size_t)(k0 + kk) * N + n0 + cl]);  // coalesced in n
    }
    __syncthreads();
    #pragma unroll
    for (int p = 0; p < 16; p++) {
        int nn = p * 4 + rw;
        Wt[(size_t)(n0 + nn) * K + k0 + cl] = T[nn][cl];       // coalesced in k
    }
}

// -------- gather + LayerNorm1, per (b, image-row hs), coalesced ------------
__global__ __launch_bounds__(256) void k_ln1(const float* __restrict__ x,
                                             const float* __restrict__ g,
                                             const float* __restrict__ bt,
                                             unsigned short* __restrict__ ln1) {
    int blk = blockIdx.x;           // b*64 + hs
    int b  = blk >> 6, hs = blk & 63;
    int t  = threadIdx.x;
    int w  = t & 63, cg = t >> 6;   // pixel, channel-group (4)
    const float* row = x + (size_t)b * DIM * 4096 + hs * 64;

    float sum = 0.f, sq = 0.f;
    for (int i = 0; i < 96; i++) {
        int c = i * 4 + cg;
        float v = row[(size_t)c * 4096 + w];
        sum += v; sq += v * v;
    }
    __shared__ float red[2][4][64];
    __shared__ float mean_s[64], rstd_s[64];
    red[0][cg][w] = sum; red[1][cg][w] = sq;
    __syncthreads();
    if (t < 64) {
        float s  = red[0][0][t] + red[0][1][t] + red[0][2][t] + red[0][3][t];
        float q2 = red[1][0][t] + red[1][1][t] + red[1][2][t] + red[1][3][t];
        float mean = s * (1.0f / DIM);
        float var  = q2 * (1.0f / DIM) - mean * mean;
        mean_s[t] = mean;
        rstd_s[t] = rsqrtf(var + 1e-5f);
    }
    __syncthreads();

    int wp = t >> 2, seg = t & 3;
    int hr = (hs + 60) & 63, wr = (wp + 60) & 63;
    int tok = ((b * 8 + (hr >> 3)) * 8 + (wr >> 3)) * 64 + (hr & 7) * 8 + (wr & 7);

    __shared__ __align__(16) unsigned short tile[64][72];
    for (int chunk = 0; chunk < 6; chunk++) {
        float mean = mean_s[w], rstd = rstd_s[w];
        #pragma unroll
        for (int it = 0; it < 16; it++) {
            int cl = it * 4 + cg;
            int c  = chunk * 64 + cl;
            float v = row[(size_t)c * 4096 + w];
            tile[w][cl] = f2bf((v - mean) * rstd * g[c] + bt[c]);
        }
        __syncthreads();
        u16x8 v0 = *(const u16x8*)&tile[wp][seg * 16];
        u16x8 v1 = *(const u16x8*)&tile[wp][seg * 16 + 8];
        unsigned short* op = ln1 + (size_t)tok * DIM + chunk * 64 + seg * 16;
        *(u16x8*)op = v0;
        *(u16x8*)(op + 8) = v1;
        __syncthreads();
    }
}

// ---------------- MFMA GEMM: C[M,N] = A[M,K](bf16) * Bt[N,K]^T(bf16) + bias
// 128x128 tile, 4 waves, 4x4 16x16x32 MFMA.
// BK=32, ring-3 LDS staging, prefetch depth 2 with counted vmcnt(8)
// (best-measured structure: R3, 91us on MLP1).
// bf16 epilogues (EPI 0/1/4) bounce the C-tile through LDS (XOR-swizzled)
// so all HBM writes are full-line u16x8.
// EPI: 0 bias->bf16; 1 bias+gelu->bf16; 2 bias+residual gather->f32;
//      3 bias->f32; 4 bias->bf16 scattered to [qkv][head][tok][48];
//      5 bias->f32 scattered DIRECTLY to out[b][c][h][w] (fuses k_out)
template <int EPI>
__global__ __launch_bounds__(256) void k_gemm_mfma(
        const unsigned short* __restrict__ A,
        const unsigned short* __restrict__ Bt,
        const float* __restrict__ bias,
        void* __restrict__ Cout,
        const float* __restrict__ xres,
        int N, int K, int GX) {
    // staging: A bufs [3][4096] u16 at 0; B bufs [3][4096] u16 at 12288.
    // bounce views (after K-loop, reuse SH):
    //   bf16 EPIs: [128][136] u16 (34816 B); EPI5: [128][68] f32 (34816 B)
    __shared__ __align__(16) unsigned short SH[24576];   // 48 KB
    int tid  = threadIdx.x;
    int lane = tid & 63;
    int wave = tid >> 6;
    int wm = wave >> 1, wn = wave & 1;
    int quad = lane >> 4, l15 = lane & 15;

    int l   = blockIdx.x;
    int xcd = l & 7;
    int r_  = l >> 3;
    int bx  = r_ % GX;
    int by  = (r_ / GX) * 8 + xcd;
    int m0 = by * 128, n0 = bx * 128;

    const unsigned short* gA0 = A  + (size_t)(m0 +      lane) * K + wave * 8;
    const unsigned short* gA1 = A  + (size_t)(m0 + 64 + lane) * K + wave * 8;
    const unsigned short* gB0 = Bt + (size_t)(n0 +      lane) * K + wave * 8;
    const unsigned short* gB1 = Bt + (size_t)(n0 + 64 + lane) * K + wave * 8;

    auto stage = [&](int buf) {
        __builtin_amdgcn_global_load_lds(
            (const __attribute__((address_space(1))) void*)gA0,
            (__attribute__((address_space(3))) void*)&SH[buf * 4096 + wave * 1024],
            16, 0, 0);
        __builtin_amdgcn_global_load_lds(
            (const __attribute__((address_space(1))) void*)gA1,
            (__attribute__((address_space(3))) void*)&SH[buf * 4096 + wave * 1024 + 512],
            16, 0, 0);
        __builtin_amdgcn_global_load_lds(
            (const __attribute__((address_space(1))) void*)gB0,
            (__attribute__((address_space(3))) void*)&SH[12288 + buf * 4096 + wave * 1024],
            16, 0, 0);
        __builtin_amdgcn_global_load_lds(
            (const __attribute__((address_space(1))) void*)gB1,
            (__attribute__((address_space(3))) void*)&SH[12288 + buf * 4096 + wave * 1024 + 512],
            16, 0, 0);
        gA0 += 32; gA1 += 32; gB0 += 32; gB1 += 32;   // advance one BK=32 step
    };

    f32x4 acc[4][4] = {};
    int nsteps = K >> 5;

    stage(0);
    stage(1);
    int cur = 0, nxt = 2;
    for (int t = 0; t < nsteps; ++t) {
        // all waves done reading buf[nxt] (it was `cur` two steps ago)
        __builtin_amdgcn_s_barrier();
        if (t + 2 < nsteps) {
            stage(nxt);
            if (++nxt == 3) nxt = 0;
            // own stage(t) loads landed; stages t+1,t+2 (8 loads) in flight
            asm volatile("s_waitcnt vmcnt(8)" ::: "memory");
        } else if (t + 2 == nsteps) {
            asm volatile("s_waitcnt vmcnt(4)" ::: "memory");
        } else {
            asm volatile("s_waitcnt vmcnt(0)" ::: "memory");
        }
        // all waves' stage(t) writes to buf[cur] visible
        __builtin_amdgcn_s_barrier();

        bf16x8 af[4], bfr[4];
        #pragma unroll
        for (int r = 0; r < 4; r++)
            af[r] = *(const bf16x8*)&SH[cur * 4096 + (quad * 128 + wm * 64 + r * 16 + l15) * 8];
        #pragma unroll
        for (int r2 = 0; r2 < 4; r2++)
            bfr[r2] = *(const bf16x8*)&SH[12288 + cur * 4096 + (quad * 128 + wn * 64 + r2 * 16 + l15) * 8];
        #pragma unroll
        for (int r = 0; r < 4; r++)
            #pragma unroll
            for (int r2 = 0; r2 < 4; r2++)
                acc[r][r2] = __builtin_amdgcn_mfma_f32_16x16x32_bf16(
                                 af[r], bfr[r2], acc[r][r2], 0, 0, 0);
        if (++cur == 3) cur = 0;
    }

    if (EPI == 2 || EPI == 3) {
        // f32 outputs: 16 lanes x 4B = full 64B lines already
        #pragma unroll
        for (int r2 = 0; r2 < 4; r2++) {
            int n = n0 + wn * 64 + r2 * 16 + l15;
            float bn = bias[n];
            #pragma unroll
            for (int r = 0; r < 4; r++) {
                #pragma unroll
                for (int reg = 0; reg < 4; reg++) {
                    int m = m0 + wm * 64 + r * 16 + quad * 4 + reg;
                    float v = acc[r][r2][reg] + bn;
                    if (EPI == 2) {
                        int b, hs, ws_;
                        tok2src(m, b, hs, ws_);
                        v += xres[(((size_t)b * DIM + n) * 64 + hs) * 64 + ws_];
                    }
                    ((float*)Cout)[(size_t)m * N + n] = v;
                }
            }
        }
    } else if (EPI == 5) {
        // fused un-permute: write f32 directly to out[b][c][hs][ws].
        // 128-token tile = two 8x8 windows of one image (same b, hi; wi, wi+1).
        // Bounce [c][tok]-major f32 so stores are float4 runs along ws.
        float* SF = (float*)SH;              // [128][68] f32 = 34816 B
        __syncthreads();                     // staging reads done
        int b    = m0 >> 12;
        int win0 = m0 >> 6;                  // global window index of half 0
        #pragma unroll
        for (int h2 = 0; h2 < 2; h2++) {
            if (wm == h2) {
                #pragma unroll
                for (int r2 = 0; r2 < 4; r2++) {
                    int c = wn * 64 + r2 * 16 + l15;
                    float bn = bias[n0 + c];
                    #pragma unroll
                    for (int r = 0; r < 4; r++) {
                        f32x4 v4;
                        #pragma unroll
                        for (int reg = 0; reg < 4; reg++)
                            v4[reg] = acc[r][r2][reg] + bn;
                        *(f32x4*)&SF[c * 68 + r * 16 + quad * 4] = v4;
                    }
                }
            }
            __syncthreads();
            int win = win0 + h2;
            int wi = win & 7, hi = (win >> 3) & 7;
            #pragma unroll
            for (int i = 0; i < 4; i++) {
                int id = tid + i * 256;          // [0,1024): c 0..127, r 0..7
                int c  = id >> 3, r = id & 7;
                f32x4 v0 = *(const f32x4*)&SF[c * 68 + r * 8];
                f32x4 v1 = *(const f32x4*)&SF[c * 68 + r * 8 + 4];
                int hs  = (hi * 8 + r + 4) & 63;
                int ws0 = wi * 8 + 4;            // <= 60, no wrap in run
                int ws1 = (wi * 8 + 8) & 63;     // wraps only at wi==7
                float* dst = (float*)Cout + ((size_t)(b * DIM + n0 + c) * 64 + hs) * 64;
                *(f32x4*)&dst[ws0] = v0;
                *(f32x4*)&dst[ws1] = v1;
            }
            __syncthreads();
        }
    } else {
        // bf16 outputs: bounce through LDS for full-line coalesced stores.
        // XOR-swizzle (32B toggle on row bit 3) -> quads hit disjoint banks.
        __syncthreads();   // all waves done reading staging LDS
        #pragma unroll
        for (int r2 = 0; r2 < 4; r2++) {
            int col = wn * 64 + r2 * 16 + l15;
            float bn = bias[n0 + col];
            #pragma unroll
            for (int r = 0; r < 4; r++) {
                int row0 = wm * 64 + r * 16 + quad * 4;
                #pragma unroll
                for (int reg = 0; reg < 4; reg++) {
                    int row = row0 + reg;
                    float v = acc[r][r2][reg] + bn;
                    if (EPI == 1) v = gelu(v);
                    SH[(row * 136 + col) ^ (((row >> 3) & 1) << 4)] = f2bf(v);
                }
            }
        }
        __syncthreads();
        #pragma unroll
        for (int i = 0; i < 8; i++) {
            int chunk = tid + i * 256;        // [0, 2048)
            int m = chunk >> 4, nc = chunk & 15;
            int idx = (m * 136 + nc * 8) ^ (((m >> 3) & 1) << 4);
            u16x8 v = *(const u16x8*)&SH[idx];
            if (EPI == 4) {
                int n = n0 + nc * 8;
                int qi  = n / 384;
                int rem = n - qi * 384;
                int hh  = rem / 48;
                int d   = rem - hh * 48;      // 8-chunks never cross 48-boundary
                *(u16x8*)&((unsigned short*)Cout)[((size_t)(qi * 8 + hh) * NTOK + m0 + m) * 48 + d] = v;
            } else {
                *(u16x8*)&((unsigned short*)Cout)[(size_t)(m0 + m) * N + n0 + nc * 8] = v;
            }
        }
    }
}

// ---------------- MFMA attention: 1 block = 1 window, 4 waves x 2 heads -----
// qkvh layout: [qkv(3)][head(8)][tok(32768)][48] bf16.
__global__ __launch_bounds__(256) void k_attn_mfma(
        const unsigned short* __restrict__ qkvh,
        unsigned short* __restrict__ attn) {
    // per-wave LDS: VT [48][72] (3456 u16) + P [64][72] (4608 u16) = 8064 u16
    __shared__ __align__(16) unsigned short lds[4][8064];   // 64512 B total
    int tid  = threadIdx.x;
    int lane = tid & 63;
    int wave = tid >> 6;
    int quad = lane >> 4, l15 = lane & 15;
    int win  = blockIdx.x;
    int tok0 = win * 64;
    unsigned short* VT = &lds[wave][0];
    unsigned short* P  = &lds[wave][3456];
    const float scale = 0.14433756729740643f;  // 48^-0.5

    for (int hi = 0; hi < 2; hi++) {
        int h = wave + hi * 4;
        const unsigned short* qb = qkvh + ((size_t)(0 * 8 + h) * NTOK + tok0) * 48;
        const unsigned short* kb = qkvh + ((size_t)(1 * 8 + h) * NTOK + tok0) * 48;
        const unsigned short* vb = qkvh + ((size_t)(2 * 8 + h) * NTOK + tok0) * 48;

        // stage V^T into LDS: lane = token, write column `lane`
        #pragma unroll
        for (int i = 0; i < 6; i++) {
            u16x8 v = *(const u16x8*)&vb[lane * 48 + i * 8];
            #pragma unroll
            for (int j = 0; j < 8; j++)
                VT[(i * 8 + j) * 72 + lane] = v[j];
        }

        // K fragments (B-operand of QK^T): kf[ni][chunk]
        bf16x8 kf[4][2];
        #pragma unroll
        for (int ni = 0; ni < 4; ni++) {
            kf[ni][0] = *(const bf16x8*)&kb[(ni * 16 + l15) * 48 + quad * 8];
            bf16x8 z = {};
            if (quad < 2)
                z = *(const bf16x8*)&kb[(ni * 16 + l15) * 48 + 32 + quad * 8];
            kf[ni][1] = z;   // d in [48,64) zero-masked
        }

        // S = Q K^T   (64x64, K=48 padded to 64 with zeros)
        f32x4 sacc[4][4] = {};
        #pragma unroll
        for (int mi = 0; mi < 4; mi++) {
            bf16x8 qf0 = *(const bf16x8*)&qb[(mi * 16 + l15) * 48 + quad * 8];
            bf16x8 qf1 = {};
            if (quad < 2)
                qf1 = *(const bf16x8*)&qb[(mi * 16 + l15) * 48 + 32 + quad * 8];
            #pragma unroll
            for (int ni = 0; ni < 4; ni++) {
                sacc[mi][ni] = __builtin_amdgcn_mfma_f32_16x16x32_bf16(qf0, kf[ni][0], sacc[mi][ni], 0, 0, 0);
                sacc[mi][ni] = __builtin_amdgcn_mfma_f32_16x16x32_bf16(qf1, kf[ni][1], sacc[mi][ni], 0, 0, 0);
            }
        }

        // softmax over rows (C-layout: row=quad*4+reg, col=ni*16+l15), P -> LDS
        #pragma unroll
        for (int mi = 0; mi < 4; mi++) {
            #pragma unroll
            for (int reg = 0; reg < 4; reg++) {
                float s0 = sacc[mi][0][reg] * scale;
                float s1 = sacc[mi][1][reg] * scale;
                float s2 = sacc[mi][2][reg] * scale;
                float s3 = sacc[mi][3][reg] * scale;
                float mx = fmaxf(fmaxf(s0, s1), fmaxf(s2, s3));
                #pragma unroll
                for (int off = 1; off < 16; off <<= 1)
                    mx = fmaxf(mx, __shfl_xor(mx, off));
                float e0 = __expf(s0 - mx);
                float e1 = __expf(s1 - mx);
                float e2 = __expf(s2 - mx);
                float e3 = __expf(s3 - mx);
                float sm = e0 + e1 + e2 + e3;
                #pragma unroll
                for (int off = 1; off < 16; off <<= 1)
                    sm += __shfl_xor(sm, off);
                float inv = 1.0f / sm;
                int row = mi * 16 + quad * 4 + reg;
                P[row * 72 +  0 + l15] = f2bf(e0 * inv);
                P[row * 72 + 16 + l15] = f2bf(e1 * inv);
                P[row * 72 + 32 + l15] = f2bf(e2 * inv);
                P[row * 72 + 48 + l15] = f2bf(e3 * inv);
            }
        }

        // O = P V   (64x48, K=64); V^T fragments from LDS
        bf16x8 vf[3][2];
        #pragma unroll
        for (int ni = 0; ni < 3; ni++)
            #pragma unroll
            for (int kt = 0; kt < 2; kt++)
                vf[ni][kt] = *(const bf16x8*)&VT[(ni * 16 + l15) * 72 + kt * 32 + quad * 8];

        #pragma unroll
        for (int mi = 0; mi < 4; mi++) {
            bf16x8 pf0 = *(const bf16x8*)&P[(mi * 16 + l15) * 72 + quad * 8];
            bf16x8 pf1 = *(const bf16x8*)&P[(mi * 16 + l15) * 72 + 32 + quad * 8];
            f32x4 o[3] = {};
            #pragma unroll
            for (int ni = 0; ni < 3; ni++) {
                o[ni] = __builtin_amdgcn_mfma_f32_16x16x32_bf16(pf0, vf[ni][0], o[ni], 0, 0, 0);
                o[ni] = __builtin_amdgcn_mfma_f32_16x16x32_bf16(pf1, vf[ni][1], o[ni], 0, 0, 0);
            }
            #pragma unroll
            for (int ni = 0; ni < 3; ni++)
                #pragma unroll
                for (int reg = 0; reg < 4; reg++) {
                    int tok = tok0 + mi * 16 + quad * 4 + reg;
                    attn[(size_t)tok * DIM + h * HD + ni * 16 + l15] = f2bf(o[ni][reg]);
                }
        }
    }
}

// ---------------- LayerNorm2 over y (f32) -> ln2 (bf16) ----------
__global__ __launch_bounds__(64) void k_ln2(const float* __restrict__ y,
                                            const float* __restrict__ g,
                                            const float* __restrict__ bt,
                                            unsigned short* __restrict__ out) {
    int tok = blockIdx.x;
    int t   = threadIdx.x;
    const float* row = y + (size_t)tok * DIM;
    float v[6];
    float sum = 0.f, sq = 0.f;
    #pragma unroll
    for (int i = 0; i < 6; i++) {
        v[i] = row[i * 64 + t];
        sum += v[i]; sq += v[i] * v[i];
    }
    #pragma unroll
    for (int o = 32; o > 0; o >>= 1) {
        sum += __shfl_xor(sum, o, 64);
        sq  += __shfl_xor(sq, o, 64);
    }
    float mean = sum * (1.0f / DIM);
    float var  = sq * (1.0f / DIM) - mean * mean;
    float rstd = rsqrtf(var + 1e-5f);
    unsigned short* orow = out + (size_t)tok * DIM;
    #pragma unroll
    for (int i = 0; i < 6; i++) {
        int c = i * 64 + t;
        orow[c] = f2bf((v[i] - mean) * rstd * g[c] + bt[c]);
    }
}

extern "C" void kernel_launch(void* const* d_in, const int* in_sizes, int n_in,
                              void* d_out, int out_size, void* d_ws, size_t ws_size,
                              hipStream_t stream) {
    const float* x      = (const float*)d_in[0];
    const float* qkv_w  = (const float*)d_in[1];
    const float* qkv_b  = (const float*)d_in[2];
    const float* proj_w = (const float*)d_in[3];
    const float* proj_b = (const float*)d_in[4];
    const float* ln1_g  = (const float*)d_in[5];
    const float* ln1_b  = (const float*)d_in[6];
    const float* ln2_g  = (const float*)d_in[7];
    const float* ln2_b  = (const float*)d_in[8];
    const float* w1     = (const float*)d_in[9];
    const float* b1     = (const float*)d_in[10];
    const float* w2     = (const float*)d_in[11];
    const float* b2     = (const float*)d_in[12];

    char* ws = (char*)d_ws;
    unsigned short* qkv_wt  = (unsigned short*)(ws + 0);
    unsigned short* proj_wt = (unsigned short*)(ws + 884736);
    unsigned short* w1t     = (unsigned short*)(ws + 1179648);
    unsigned short* w2t     = (unsigned short*)(ws + 2359296);
    unsigned short* ln1     = (unsigned short*)(ws + 4194304);
    unsigned short* qkv     = (unsigned short*)(ws + 29360128);   // [3][8][32768][48]
    unsigned short* attn    = (unsigned short*)(ws + 104857600);
    float*          y       = (float*)(ws + 130023424);
    unsigned short* ln2     = ln1;
    unsigned short* mid     = qkv;      // [32768][1536] bf16

    k_wt4<<<432, 256, 0, stream>>>(qkv_w, proj_w, w1, w2, qkv_wt, proj_wt, w1t, w2t);
    k_ln1<<<512, 256, 0, stream>>>(x, ln1_g, ln1_b, ln1);
    k_gemm_mfma<4><<<9 * 256, 256, 0, stream>>>(ln1, qkv_wt, qkv_b, qkv, nullptr, 1152, 384, 9);
    k_attn_mfma<<<NWIN, 256, 0, stream>>>(qkv, attn);
    k_gemm_mfma<2><<<3 * 256, 256, 0, stream>>>(attn, proj_wt, proj_b, y, x, 384, 384, 3);
    k_ln2<<<NTOK, 64, 0, stream>>>(y, ln2_g, ln2_b, ln2);
    k_gemm_mfma<1><<<12 * 256, 256, 0, stream>>>(ln2, w1t, b1, mid, nullptr, 1536, 384, 12);
    k_gemm_mfma<5><<<3 * 256, 256, 0, stream>>>(mid, w2t, b2, (float*)d_out, nullptr, 384, 1536, 3);
}

// Round 7
// 459.062 us; speedup vs baseline: 1.5081x; 1.0641x over previous
//
#include <hip/hip_runtime.h>
#include <hip/hip_bf16.h>
#include <math.h>

#define DIM   384
#define HEADS 8
#define HD    48
#define NTOK  32768   // 8 * 64 * 64
#define NWIN  512     // 8 images * 64 windows

typedef __attribute__((ext_vector_type(8))) short bf16x8;
typedef __attribute__((ext_vector_type(8))) unsigned short u16x8;
typedef __attribute__((ext_vector_type(4))) float f32x4;

__device__ __forceinline__ float bf2f(unsigned short u) {
    unsigned int v = ((unsigned int)u) << 16;
    return __uint_as_float(v);
}
// RNE f32->bf16 via native cast (proven bit-identical in R5/R6 bench)
__device__ __forceinline__ unsigned short f2bf(float f) {
    __bf16 b = (__bf16)f;
    return __builtin_bit_cast(unsigned short, b);
}

// branchless erf-based GELU (A&S 7.1.25 3-term, |err_erf| < 2.5e-5 << bf16 ulp)
__device__ __forceinline__ float gelu(float v) {
    float z  = v * 0.70710678118654752f;
    float az = fabsf(z);
    float t  = __builtin_amdgcn_rcpf(1.0f + 0.47047f * az);
    float p  = t * (0.3480242f + t * (-0.0958798f + t * 0.7478556f));
    float ea = 1.0f - p * __expf(-az * az);
    float er = copysignf(ea, z);
    return 0.5f * v * (1.0f + er);
}

// token (window order) -> source pixel of x (accounting for roll by -SHIFT)
__device__ __forceinline__ void tok2src(int tok, int& b, int& hs, int& ws) {
    int bb  = tok >> 12;
    int win = (tok >> 6) & 63;
    int t   = tok & 63;
    int hi = win >> 3, wi = win & 7;
    int r  = t >> 3,  cc = t & 7;
    b  = bb;
    hs = (hi * 8 + r  + 4) & 63;
    ws = (wi * 8 + cc + 4) & 63;
}

// ------------- weight convert f32 [K][N] -> bf16 [N][K], coalesced both
// sides via 64x64 LDS tile transpose. One block = one 64x64 tile.
__global__ __launch_bounds__(256) void k_wt4(const float* __restrict__ qkv_w,
                                             const float* __restrict__ proj_w,
                                             const float* __restrict__ w1,
                                             const float* __restrict__ w2,
                                             unsigned short* __restrict__ d0,
                                             unsigned short* __restrict__ d1,
                                             unsigned short* __restrict__ d2,
                                             unsigned short* __restrict__ d3) {
    // tiles: qkv 6x18=108 | proj 6x6=36 | w1 6x24=144 | w2 24x6=144  => 432
    __shared__ unsigned short T[64][66];
    int b = blockIdx.x;
    const float* W; unsigned short* Wt; int K, N, lt;
    if (b < 108)      { W = qkv_w;  Wt = d0; K = 384;  N = 1152; lt = b; }
    else if (b < 144) { W = proj_w; Wt = d1; K = 384;  N = 384;  lt = b - 108; }
    else if (b < 288) { W = w1;     Wt = d2; K = 384;  N = 1536; lt = b - 144; }
    else              { W = w2;     Wt = d3; K = 1536; N = 384;  lt = b - 288; }
    int tn = N >> 6;
    int k0 = (lt / tn) << 6, n0 = (lt % tn) << 6;
    int t  = threadIdx.x;
    int cl = t & 63, rw = t >> 6;
    #pragma unroll
    for (int p = 0; p < 16; p++) {
        int kk = p * 4 + rw;
        T[cl][kk] = f2bf(W[(size_t)(k0 + kk) * N + n0 + cl]);  // coalesced in n
    }
    __syncthreads();
    #pragma unroll
    for (int p = 0; p < 16; p++) {
        int nn = p * 4 + rw;
        Wt[(size_t)(n0 + nn) * K + k0 + cl] = T[nn][cl];       // coalesced in k
    }
}

// -------- gather + LayerNorm1, per (b, image-row hs), coalesced ------------
__global__ __launch_bounds__(256) void k_ln1(const float* __restrict__ x,
                                             const float* __restrict__ g,
                                             const float* __restrict__ bt,
                                             unsigned short* __restrict__ ln1) {
    int blk = blockIdx.x;           // b*64 + hs
    int b  = blk >> 6, hs = blk & 63;
    int t  = threadIdx.x;
    int w  = t & 63, cg = t >> 6;   // pixel, channel-group (4)
    const float* row = x + (size_t)b * DIM * 4096 + hs * 64;

    float sum = 0.f, sq = 0.f;
    for (int i = 0; i < 96; i++) {
        int c = i * 4 + cg;
        float v = row[(size_t)c * 4096 + w];
        sum += v; sq += v * v;
    }
    __shared__ float red[2][4][64];
    __shared__ float mean_s[64], rstd_s[64];
    red[0][cg][w] = sum; red[1][cg][w] = sq;
    __syncthreads();
    if (t < 64) {
        float s  = red[0][0][t] + red[0][1][t] + red[0][2][t] + red[0][3][t];
        float q2 = red[1][0][t] + red[1][1][t] + red[1][2][t] + red[1][3][t];
        float mean = s * (1.0f / DIM);
        float var  = q2 * (1.0f / DIM) - mean * mean;
        mean_s[t] = mean;
        rstd_s[t] = rsqrtf(var + 1e-5f);
    }
    __syncthreads();

    int wp = t >> 2, seg = t & 3;
    int hr = (hs + 60) & 63, wr = (wp + 60) & 63;
    int tok = ((b * 8 + (hr >> 3)) * 8 + (wr >> 3)) * 64 + (hr & 7) * 8 + (wr & 7);

    __shared__ __align__(16) unsigned short tile[64][72];
    for (int chunk = 0; chunk < 6; chunk++) {
        float mean = mean_s[w], rstd = rstd_s[w];
        #pragma unroll
        for (int it = 0; it < 16; it++) {
            int cl = it * 4 + cg;
            int c  = chunk * 64 + cl;
            float v = row[(size_t)c * 4096 + w];
            tile[w][cl] = f2bf((v - mean) * rstd * g[c] + bt[c]);
        }
        __syncthreads();
        u16x8 v0 = *(const u16x8*)&tile[wp][seg * 16];
        u16x8 v1 = *(const u16x8*)&tile[wp][seg * 16 + 8];
        unsigned short* op = ln1 + (size_t)tok * DIM + chunk * 64 + seg * 16;
        *(u16x8*)op = v0;
        *(u16x8*)(op + 8) = v1;
        __syncthreads();
    }
}

// ---------------- MFMA GEMM: C[M,N] = A[M,K](bf16) * Bt[N,K]^T(bf16) + bias
// 128x128 tile, 4 waves, 4x4 16x16x32 MFMA.
// BK=32, ring-3 LDS staging, prefetch depth 2 with counted vmcnt(8)
// (best-measured structure: R3, 91us on MLP1).
// bf16 epilogues (EPI 0/1/4) bounce the C-tile through LDS (XOR-swizzled)
// so all HBM writes are full-line u16x8.
// EPI: 0 bias->bf16; 1 bias+gelu->bf16;
//      2 bias+residual gather->f32 rows stored PIXEL-RASTER (p=(b*64+hs)*64+ws);
//      3 bias->f32; 4 bias->bf16 scattered to [qkv][head][tok][48];
//      5 bias->f32, M already pixel-raster, writes out[b][c][hs][ws]
//        as full 256B-aligned ws-runs (no partial lines, no RMW)
template <int EPI>
__global__ __launch_bounds__(256) void k_gemm_mfma(
        const unsigned short* __restrict__ A,
        const unsigned short* __restrict__ Bt,
        const float* __restrict__ bias,
        void* __restrict__ Cout,
        const float* __restrict__ xres,
        int N, int K, int GX) {
    // staging: A bufs [3][4096] u16 at 0; B bufs [3][4096] u16 at 12288.
    // bounce views (after K-loop, reuse SH):
    //   bf16 EPIs: [128][136] u16 (34816 B); EPI5: [128][68] f32 (34816 B)
    __shared__ __align__(16) unsigned short SH[24576];   // 48 KB
    int tid  = threadIdx.x;
    int lane = tid & 63;
    int wave = tid >> 6;
    int wm = wave >> 1, wn = wave & 1;
    int quad = lane >> 4, l15 = lane & 15;

    int l   = blockIdx.x;
    int xcd = l & 7;
    int r_  = l >> 3;
    int bx  = r_ % GX;
    int by  = (r_ / GX) * 8 + xcd;
    int m0 = by * 128, n0 = bx * 128;

    const unsigned short* gA0 = A  + (size_t)(m0 +      lane) * K + wave * 8;
    const unsigned short* gA1 = A  + (size_t)(m0 + 64 + lane) * K + wave * 8;
    const unsigned short* gB0 = Bt + (size_t)(n0 +      lane) * K + wave * 8;
    const unsigned short* gB1 = Bt + (size_t)(n0 + 64 + lane) * K + wave * 8;

    auto stage = [&](int buf) {
        __builtin_amdgcn_global_load_lds(
            (const __attribute__((address_space(1))) void*)gA0,
            (__attribute__((address_space(3))) void*)&SH[buf * 4096 + wave * 1024],
            16, 0, 0);
        __builtin_amdgcn_global_load_lds(
            (const __attribute__((address_space(1))) void*)gA1,
            (__attribute__((address_space(3))) void*)&SH[buf * 4096 + wave * 1024 + 512],
            16, 0, 0);
        __builtin_amdgcn_global_load_lds(
            (const __attribute__((address_space(1))) void*)gB0,
            (__attribute__((address_space(3))) void*)&SH[12288 + buf * 4096 + wave * 1024],
            16, 0, 0);
        __builtin_amdgcn_global_load_lds(
            (const __attribute__((address_space(1))) void*)gB1,
            (__attribute__((address_space(3))) void*)&SH[12288 + buf * 4096 + wave * 1024 + 512],
            16, 0, 0);
        gA0 += 32; gA1 += 32; gB0 += 32; gB1 += 32;   // advance one BK=32 step
    };

    f32x4 acc[4][4] = {};
    int nsteps = K >> 5;

    stage(0);
    stage(1);
    int cur = 0, nxt = 2;
    for (int t = 0; t < nsteps; ++t) {
        // all waves done reading buf[nxt] (it was `cur` two steps ago)
        __builtin_amdgcn_s_barrier();
        if (t + 2 < nsteps) {
            stage(nxt);
            if (++nxt == 3) nxt = 0;
            // own stage(t) loads landed; stages t+1,t+2 (8 loads) in flight
            asm volatile("s_waitcnt vmcnt(8)" ::: "memory");
        } else if (t + 2 == nsteps) {
            asm volatile("s_waitcnt vmcnt(4)" ::: "memory");
        } else {
            asm volatile("s_waitcnt vmcnt(0)" ::: "memory");
        }
        // all waves' stage(t) writes to buf[cur] visible
        __builtin_amdgcn_s_barrier();

        bf16x8 af[4], bfr[4];
        #pragma unroll
        for (int r = 0; r < 4; r++)
            af[r] = *(const bf16x8*)&SH[cur * 4096 + (quad * 128 + wm * 64 + r * 16 + l15) * 8];
        #pragma unroll
        for (int r2 = 0; r2 < 4; r2++)
            bfr[r2] = *(const bf16x8*)&SH[12288 + cur * 4096 + (quad * 128 + wn * 64 + r2 * 16 + l15) * 8];
        #pragma unroll
        for (int r = 0; r < 4; r++)
            #pragma unroll
            for (int r2 = 0; r2 < 4; r2++)
                acc[r][r2] = __builtin_amdgcn_mfma_f32_16x16x32_bf16(
                                 af[r], bfr[r2], acc[r][r2], 0, 0, 0);
        if (++cur == 3) cur = 0;
    }

    if (EPI == 2 || EPI == 3) {
        // f32 outputs: 16 lanes x 4B = full 64B lines already
        #pragma unroll
        for (int r2 = 0; r2 < 4; r2++) {
            int n = n0 + wn * 64 + r2 * 16 + l15;
            float bn = bias[n];
            #pragma unroll
            for (int r = 0; r < 4; r++) {
                #pragma unroll
                for (int reg = 0; reg < 4; reg++) {
                    int m = m0 + wm * 64 + r * 16 + quad * 4 + reg;
                    float v = acc[r][r2][reg] + bn;
                    if (EPI == 2) {
                        int b, hs, ws_;
                        tok2src(m, b, hs, ws_);
                        v += xres[(((size_t)b * DIM + n) * 64 + hs) * 64 + ws_];
                        // store row at PIXEL-RASTER index (roll absorbed here)
                        int p = (b * 64 + hs) * 64 + ws_;
                        ((float*)Cout)[(size_t)p * N + n] = v;
                    } else {
                        ((float*)Cout)[(size_t)m * N + n] = v;
                    }
                }
            }
        }
    } else if (EPI == 5) {
        // M is pixel-raster: tile = 2 image rows (hs0, hs0+1) x 64 ws of
        // image b. Bounce [c][ws] f32 -> full-line aligned ws-runs.
        float* SF = (float*)SH;              // [128][68] f32 = 34816 B
        __syncthreads();                     // staging reads done
        int b   = m0 >> 12;
        int hs0 = (m0 >> 6) & 63;
        #pragma unroll
        for (int h2 = 0; h2 < 2; h2++) {
            if (wm == h2) {
                #pragma unroll
                for (int r2 = 0; r2 < 4; r2++) {
                    int c = wn * 64 + r2 * 16 + l15;
                    float bn = bias[n0 + c];
                    #pragma unroll
                    for (int r = 0; r < 4; r++) {
                        f32x4 v4;
                        #pragma unroll
                        for (int reg = 0; reg < 4; reg++)
                            v4[reg] = acc[r][r2][reg] + bn;
                        *(f32x4*)&SF[c * 68 + r * 16 + quad * 4] = v4;  // ws = r*16+quad*4+reg
                    }
                }
            }
            __syncthreads();
            #pragma unroll
            for (int i = 0; i < 8; i++) {
                int id = tid + i * 256;          // [0,2048): c = id>>4, chunk = id&15
                int c  = id >> 4, ch = id & 15;
                f32x4 v = *(const f32x4*)&SF[c * 68 + ch * 4];
                float* dst = (float*)Cout + ((size_t)(b * DIM + n0 + c) * 64 + hs0 + h2) * 64;
                *(f32x4*)&dst[ch * 4] = v;       // 16 consecutive threads = 256B run
            }
            __syncthreads();
        }
    } else {
        // bf16 outputs: bounce through LDS for full-line coalesced stores.
        // XOR-swizzle (32B toggle on row bit 3) -> quads hit disjoint banks.
        __syncthreads();   // all waves done reading staging LDS
        #pragma unroll
        for (int r2 = 0; r2 < 4; r2++) {
            int col = wn * 64 + r2 * 16 + l15;
            float bn = bias[n0 + col];
            #pragma unroll
            for (int r = 0; r < 4; r++) {
                int row0 = wm * 64 + r * 16 + quad * 4;
                #pragma unroll
                for (int reg = 0; reg < 4; reg++) {
                    int row = row0 + reg;
                    float v = acc[r][r2][reg] + bn;
                    if (EPI == 1) v = gelu(v);
                    SH[(row * 136 + col) ^ (((row >> 3) & 1) << 4)] = f2bf(v);
                }
            }
        }
        __syncthreads();
        #pragma unroll
        for (int i = 0; i < 8; i++) {
            int chunk = tid + i * 256;        // [0, 2048)
            int m = chunk >> 4, nc = chunk & 15;
            int idx = (m * 136 + nc * 8) ^ (((m >> 3) & 1) << 4);
            u16x8 v = *(const u16x8*)&SH[idx];
            if (EPI == 4) {
                int n = n0 + nc * 8;
                int qi  = n / 384;
                int rem = n - qi * 384;
                int hh  = rem / 48;
                int d   = rem - hh * 48;      // 8-chunks never cross 48-boundary
                *(u16x8*)&((unsigned short*)Cout)[((size_t)(qi * 8 + hh) * NTOK + m0 + m) * 48 + d] = v;
            } else {
                *(u16x8*)&((unsigned short*)Cout)[(size_t)(m0 + m) * N + n0 + nc * 8] = v;
            }
        }
    }
}

// ---------------- MFMA attention: 1 block = 1 window, 4 waves x 2 heads -----
// qkvh layout: [qkv(3)][head(8)][tok(32768)][48] bf16.
__global__ __launch_bounds__(256) void k_attn_mfma(
        const unsigned short* __restrict__ qkvh,
        unsigned short* __restrict__ attn) {
    // per-wave LDS: VT [48][72] (3456 u16) + P [64][72] (4608 u16) = 8064 u16
    __shared__ __align__(16) unsigned short lds[4][8064];   // 64512 B total
    int tid  = threadIdx.x;
    int lane = tid & 63;
    int wave = tid >> 6;
    int quad = lane >> 4, l15 = lane & 15;
    int win  = blockIdx.x;
    int tok0 = win * 64;
    unsigned short* VT = &lds[wave][0];
    unsigned short* P  = &lds[wave][3456];
    const float scale = 0.14433756729740643f;  // 48^-0.5

    for (int hi = 0; hi < 2; hi++) {
        int h = wave + hi * 4;
        const unsigned short* qb = qkvh + ((size_t)(0 * 8 + h) * NTOK + tok0) * 48;
        const unsigned short* kb = qkvh + ((size_t)(1 * 8 + h) * NTOK + tok0) * 48;
        const unsigned short* vb = qkvh + ((size_t)(2 * 8 + h) * NTOK + tok0) * 48;

        // stage V^T into LDS: lane = token, write column `lane`
        #pragma unroll
        for (int i = 0; i < 6; i++) {
            u16x8 v = *(const u16x8*)&vb[lane * 48 + i * 8];
            #pragma unroll
            for (int j = 0; j < 8; j++)
                VT[(i * 8 + j) * 72 + lane] = v[j];
        }

        // K fragments (B-operand of QK^T): kf[ni][chunk]
        bf16x8 kf[4][2];
        #pragma unroll
        for (int ni = 0; ni < 4; ni++) {
            kf[ni][0] = *(const bf16x8*)&kb[(ni * 16 + l15) * 48 + quad * 8];
            bf16x8 z = {};
            if (quad < 2)
                z = *(const bf16x8*)&kb[(ni * 16 + l15) * 48 + 32 + quad * 8];
            kf[ni][1] = z;   // d in [48,64) zero-masked
        }

        // S = Q K^T   (64x64, K=48 padded to 64 with zeros)
        f32x4 sacc[4][4] = {};
        #pragma unroll
        for (int mi = 0; mi < 4; mi++) {
            bf16x8 qf0 = *(const bf16x8*)&qb[(mi * 16 + l15) * 48 + quad * 8];
            bf16x8 qf1 = {};
            if (quad < 2)
                qf1 = *(const bf16x8*)&qb[(mi * 16 + l15) * 48 + 32 + quad * 8];
            #pragma unroll
            for (int ni = 0; ni < 4; ni++) {
                sacc[mi][ni] = __builtin_amdgcn_mfma_f32_16x16x32_bf16(qf0, kf[ni][0], sacc[mi][ni], 0, 0, 0);
                sacc[mi][ni] = __builtin_amdgcn_mfma_f32_16x16x32_bf16(qf1, kf[ni][1], sacc[mi][ni], 0, 0, 0);
            }
        }

        // softmax over rows (C-layout: row=quad*4+reg, col=ni*16+l15), P -> LDS
        #pragma unroll
        for (int mi = 0; mi < 4; mi++) {
            #pragma unroll
            for (int reg = 0; reg < 4; reg++) {
                float s0 = sacc[mi][0][reg] * scale;
                float s1 = sacc[mi][1][reg] * scale;
                float s2 = sacc[mi][2][reg] * scale;
                float s3 = sacc[mi][3][reg] * scale;
                float mx = fmaxf(fmaxf(s0, s1), fmaxf(s2, s3));
                #pragma unroll
                for (int off = 1; off < 16; off <<= 1)
                    mx = fmaxf(mx, __shfl_xor(mx, off));
                float e0 = __expf(s0 - mx);
                float e1 = __expf(s1 - mx);
                float e2 = __expf(s2 - mx);
                float e3 = __expf(s3 - mx);
                float sm = e0 + e1 + e2 + e3;
                #pragma unroll
                for (int off = 1; off < 16; off <<= 1)
                    sm += __shfl_xor(sm, off);
                float inv = 1.0f / sm;
                int row = mi * 16 + quad * 4 + reg;
                P[row * 72 +  0 + l15] = f2bf(e0 * inv);
                P[row * 72 + 16 + l15] = f2bf(e1 * inv);
                P[row * 72 + 32 + l15] = f2bf(e2 * inv);
                P[row * 72 + 48 + l15] = f2bf(e3 * inv);
            }
        }

        // O = P V   (64x48, K=64); V^T fragments from LDS
        bf16x8 vf[3][2];
        #pragma unroll
        for (int ni = 0; ni < 3; ni++)
            #pragma unroll
            for (int kt = 0; kt < 2; kt++)
                vf[ni][kt] = *(const bf16x8*)&VT[(ni * 16 + l15) * 72 + kt * 32 + quad * 8];

        #pragma unroll
        for (int mi = 0; mi < 4; mi++) {
            bf16x8 pf0 = *(const bf16x8*)&P[(mi * 16 + l15) * 72 + quad * 8];
            bf16x8 pf1 = *(const bf16x8*)&P[(mi * 16 + l15) * 72 + 32 + quad * 8];
            f32x4 o[3] = {};
            #pragma unroll
            for (int ni = 0; ni < 3; ni++) {
                o[ni] = __builtin_amdgcn_mfma_f32_16x16x32_bf16(pf0, vf[ni][0], o[ni], 0, 0, 0);
                o[ni] = __builtin_amdgcn_mfma_f32_16x16x32_bf16(pf1, vf[ni][1], o[ni], 0, 0, 0);
            }
            #pragma unroll
            for (int ni = 0; ni < 3; ni++)
                #pragma unroll
                for (int reg = 0; reg < 4; reg++) {
                    int tok = tok0 + mi * 16 + quad * 4 + reg;
                    attn[(size_t)tok * DIM + h * HD + ni * 16 + l15] = f2bf(o[ni][reg]);
                }
        }
    }
}

// ---------------- LayerNorm2 over y (f32) -> ln2 (bf16), row-order agnostic --
__global__ __launch_bounds__(64) void k_ln2(const float* __restrict__ y,
                                            const float* __restrict__ g,
                                            const float* __restrict__ bt,
                                            unsigned short* __restrict__ out) {
    int tok = blockIdx.x;
    int t   = threadIdx.x;
    const float* row = y + (size_t)tok * DIM;
    float v[6];
    float sum = 0.f, sq = 0.f;
    #pragma unroll
    for (int i = 0; i < 6; i++) {
        v[i] = row[i * 64 + t];
        sum += v[i]; sq += v[i] * v[i];
    }
    #pragma unroll
    for (int o = 32; o > 0; o >>= 1) {
        sum += __shfl_xor(sum, o, 64);
        sq  += __shfl_xor(sq, o, 64);
    }
    float mean = sum * (1.0f / DIM);
    float var  = sq * (1.0f / DIM) - mean * mean;
    float rstd = rsqrtf(var + 1e-5f);
    unsigned short* orow = out + (size_t)tok * DIM;
    #pragma unroll
    for (int i = 0; i < 6; i++) {
        int c = i * 64 + t;
        orow[c] = f2bf((v[i] - mean) * rstd * g[c] + bt[c]);
    }
}

extern "C" void kernel_launch(void* const* d_in, const int* in_sizes, int n_in,
                              void* d_out, int out_size, void* d_ws, size_t ws_size,
                              hipStream_t stream) {
    const float* x      = (const float*)d_in[0];
    const float* qkv_w  = (const float*)d_in[1];
    const float* qkv_b  = (const float*)d_in[2];
    const float* proj_w = (const float*)d_in[3];
    const float* proj_b = (const float*)d_in[4];
    const float* ln1_g  = (const float*)d_in[5];
    const float* ln1_b  = (const float*)d_in[6];
    const float* ln2_g  = (const float*)d_in[7];
    const float* ln2_b  = (const float*)d_in[8];
    const float* w1     = (const float*)d_in[9];
    const float* b1     = (const float*)d_in[10];
    const float* w2     = (const float*)d_in[11];
    const float* b2     = (const float*)d_in[12];

    char* ws = (char*)d_ws;
    unsigned short* qkv_wt  = (unsigned short*)(ws + 0);
    unsigned short* proj_wt = (unsigned short*)(ws + 884736);
    unsigned short* w1t     = (unsigned short*)(ws + 1179648);
    unsigned short* w2t     = (unsigned short*)(ws + 2359296);
    unsigned short* ln1     = (unsigned short*)(ws + 4194304);
    unsigned short* qkv     = (unsigned short*)(ws + 29360128);   // [3][8][32768][48]
    unsigned short* attn    = (unsigned short*)(ws + 104857600);
    float*          y       = (float*)(ws + 130023424);  // rows = pixel-raster
    unsigned short* ln2     = ln1;
    unsigned short* mid     = qkv;      // [32768][1536] bf16, rows = pixel-raster

    k_wt4<<<432, 256, 0, stream>>>(qkv_w, proj_w, w1, w2, qkv_wt, proj_wt, w1t, w2t);
    k_ln1<<<512, 256, 0, stream>>>(x, ln1_g, ln1_b, ln1);
    k_gemm_mfma<4><<<9 * 256, 256, 0, stream>>>(ln1, qkv_wt, qkv_b, qkv, nullptr, 1152, 384, 9);
    k_attn_mfma<<<NWIN, 256, 0, stream>>>(qkv, attn);
    k_gemm_mfma<2><<<3 * 256, 256, 0, stream>>>(attn, proj_wt, proj_b, y, x, 384, 384, 3);
    k_ln2<<<NTOK, 64, 0, stream>>>(y, ln2_g, ln2_b, ln2);
    k_gemm_mfma<1><<<12 * 256, 256, 0, stream>>>(ln2, w1t, b1, mid, nullptr, 1536, 384, 12);
    k_gemm_mfma<5><<<3 * 256, 256, 0, stream>>>(mid, w2t, b2, (float*)d_out, nullptr, 384, 1536, 3);
}